// Round 10
// baseline (406.351 us; speedup 1.0000x reference)
//
#include <hip/hip_runtime.h>
#include <math.h>

#define BATCH 2
#define SEQ 4096
#define DIM 512
#define FF 2048
#define NROWS (BATCH*SEQ)
#define KT 32
#define RSQRT_D 0.044194173824159216f  /* 1/sqrt(512) */

typedef __attribute__((ext_vector_type(8))) short short8;
typedef __attribute__((ext_vector_type(4))) short short4v;
typedef __attribute__((ext_vector_type(4))) float f32x4;

// ---------------------------------------------------------------- helpers
__device__ __forceinline__ float gelu_f(float v) {
    return 0.5f * v * (1.0f + erff(v * 0.70710678118654752440f));
}
__device__ __forceinline__ short bf16b(float x) {
    union { float f; unsigned u; } c; c.f = x;
    unsigned r = (c.u + 0x7FFFu + ((c.u >> 16) & 1u)) >> 16;
    return (short)r;
}
__device__ __forceinline__ float bf16f(short h) {
    union { unsigned u; float f; } c; c.u = ((unsigned)(unsigned short)h) << 16;
    return c.f;
}
__device__ __forceinline__ void gload16(const void* g, void* l) {
    __builtin_amdgcn_global_load_lds(
        (const __attribute__((address_space(1))) unsigned int*)g,
        (__attribute__((address_space(3))) unsigned int*)l, 16, 0, 0);
}
__device__ __forceinline__ float blk_sum256(float v, volatile float* sm) {
    #pragma unroll
    for (int o = 32; o; o >>= 1) v += __shfl_xor(v, o);
    __syncthreads();
    if ((threadIdx.x & 63) == 0) sm[threadIdx.x >> 6] = v;
    __syncthreads();
    return sm[0] + sm[1] + sm[2] + sm[3];
}

// ---------------------------------------------------------------- all weights f32 -> bf16 (one launch)
__global__ __launch_bounds__(256) void f2bf_all(
        const float* __restrict__ Wq, const float* __restrict__ Wk,
        const float* __restrict__ Wv, const float* __restrict__ Wp,
        const float* __restrict__ W1, const float* __restrict__ W2,
        short* __restrict__ Wcat, short* __restrict__ Wpb,
        short* __restrict__ W1b, short* __restrict__ W2b)
{
    int i = blockIdx.x * 256 + threadIdx.x;    // 8-elem group, total 393216
    const float* src; short* dst; int loc;
    if      (i <  32768) { src = Wq; dst = Wcat;          loc = i; }
    else if (i <  65536) { src = Wk; dst = Wcat + 262144; loc = i - 32768; }
    else if (i <  98304) { src = Wv; dst = Wcat + 524288; loc = i - 65536; }
    else if (i < 131072) { src = Wp; dst = Wpb;           loc = i - 98304; }
    else if (i < 262144) { src = W1; dst = W1b;           loc = i - 131072; }
    else                 { src = W2; dst = W2b;           loc = i - 262144; }
    const float4* p = (const float4*)(src + (size_t)loc * 8);
    float4 a = p[0], b = p[1];
    short8 r;
    r[0]=bf16b(a.x); r[1]=bf16b(a.y); r[2]=bf16b(a.z); r[3]=bf16b(a.w);
    r[4]=bf16b(b.x); r[5]=bf16b(b.y); r[6]=bf16b(b.z); r[7]=bf16b(b.w);
    *(short8*)(dst + (size_t)loc * 8) = r;
}

// ---------------------------------------------------------------- layernorm (f32 in, bf16 out)
__global__ __launch_bounds__(256) void ln_kernel(const float* __restrict__ x,
        const float* __restrict__ g, const float* __restrict__ be,
        short* __restrict__ o)
{
    int row  = blockIdx.x * 4 + (threadIdx.x >> 6);
    int lane = threadIdx.x & 63;
    const float4* xr = (const float4*)(x + (size_t)row * DIM);
    float4 v0 = xr[lane*2], v1 = xr[lane*2+1];
    float s = v0.x+v0.y+v0.z+v0.w + v1.x+v1.y+v1.z+v1.w;
    #pragma unroll
    for (int off = 32; off; off >>= 1) s += __shfl_xor(s, off);
    float mu = s * (1.0f/DIM);
    float d[8] = {v0.x-mu, v0.y-mu, v0.z-mu, v0.w-mu, v1.x-mu, v1.y-mu, v1.z-mu, v1.w-mu};
    float q = 0.f;
    #pragma unroll
    for (int j = 0; j < 8; ++j) q += d[j]*d[j];
    #pragma unroll
    for (int off = 32; off; off >>= 1) q += __shfl_xor(q, off);
    float rs = rsqrtf(q * (1.0f/DIM) + 1e-5f);
    const float4* g4 = (const float4*)g;
    const float4* b4 = (const float4*)be;
    float4 ga = g4[lane*2], gb = g4[lane*2+1];
    float4 ba = b4[lane*2], bb = b4[lane*2+1];
    float gv[8] = {ga.x,ga.y,ga.z,ga.w, gb.x,gb.y,gb.z,gb.w};
    float bv[8] = {ba.x,ba.y,ba.z,ba.w, bb.x,bb.y,bb.z,bb.w};
    short8 r;
    #pragma unroll
    for (int j = 0; j < 8; ++j) r[j] = bf16b(d[j]*rs*gv[j] + bv[j]);
    *(short8*)(o + (size_t)row * DIM + lane*8) = r;
}

// ---------------------------------------------------------------- bf16 MFMA GEMM v2 (r5-exact, TAG only names the dispatch)
template<int TAG>
__global__ __launch_bounds__(256) void gemm_v2(
        const short* __restrict__ A, const short* __restrict__ W,
        const float* __restrict__ bias, const float* __restrict__ res,
        float* __restrict__ Cf, short* __restrict__ Cb,
        short* __restrict__ CbK, short* __restrict__ CbV,
        int K, int sa, int sw, int sc, int act, int accum)
{
    __shared__ short As[2][4096];
    __shared__ short Ws[2][4096];
    int tid = threadIdx.x;
    int m0 = blockIdx.y * 128, n0 = blockIdx.x * 128;
    int w = tid >> 6, lane = tid & 63;
    int wr = (w >> 1) * 64, wc = (w & 1) * 64;
    int lr = lane & 15, lg = lane >> 4;
    int srow = tid >> 2, skoff = (tid & 3) * 8;
    const short* Ab = A + (size_t)(m0 + srow) * sa + skoff;
    const short* Wb = W + (size_t)(n0 + srow) * sw + skoff;

    #define STAGE_G(buf, kk) do { \
        gload16(Ab + (kk),                    As[buf] + tid*8); \
        gload16(Ab + (size_t)64*sa + (kk),    As[buf] + 2048 + tid*8); \
        gload16(Wb + (kk),                    Ws[buf] + tid*8); \
        gload16(Wb + (size_t)64*sw + (kk),    Ws[buf] + 2048 + tid*8); } while(0)

    f32x4 acc[4][4];
    f32x4 zero = {0.f, 0.f, 0.f, 0.f};
    #pragma unroll
    for (int i = 0; i < 4; ++i)
        #pragma unroll
        for (int j = 0; j < 4; ++j) acc[i][j] = zero;

    STAGE_G(0, 0);
    __syncthreads();
    int cur = 0;
    for (int k0 = 0; k0 < K; k0 += 32) {
        if (k0 + 32 < K) STAGE_G(cur ^ 1, k0 + 32);
        short8 a[4], b[4];
        #pragma unroll
        for (int i = 0; i < 4; ++i) a[i] = *(const short8*)(As[cur] + (wr + i*16 + lr)*32 + lg*8);
        #pragma unroll
        for (int j = 0; j < 4; ++j) b[j] = *(const short8*)(Ws[cur] + (wc + j*16 + lr)*32 + lg*8);
        #pragma unroll
        for (int i = 0; i < 4; ++i)
            #pragma unroll
            for (int j = 0; j < 4; ++j)
                acc[i][j] = __builtin_amdgcn_mfma_f32_16x16x32_bf16(a[i], b[j], acc[i][j], 0, 0, 0);
        __syncthreads();
        cur ^= 1;
    }
    #undef STAGE_G

    #pragma unroll
    for (int i = 0; i < 4; ++i) {
        #pragma unroll
        for (int r = 0; r < 4; ++r) {
            size_t m = (size_t)m0 + wr + i*16 + lg*4 + r;
            #pragma unroll
            for (int j = 0; j < 4; ++j) {
                int n = n0 + wc + j*16 + lr;
                float v = acc[i][j][r];
                if (bias) v += bias[n];
                if (act)  v = gelu_f(v);
                if (CbK) {
                    int seg = n >> 9, nl = n & 511;
                    short* dst = (seg == 0) ? Cb : (seg == 1) ? CbK : CbV;
                    dst[m * 512 + nl] = bf16b(v);
                } else {
                    if (res) v += res[m * sc + n];
                    size_t idx = m * sc + n;
                    if (Cf) { if (accum) Cf[idx] += v; else Cf[idx] = v; }
                    if (Cb) Cb[idx] = bf16b(v);
                }
            }
        }
    }
}

// ---------------------------------------------------------------- bf16 tile transpose V[b][l][d] -> Vt[b][d][l]
__global__ __launch_bounds__(256) void vtrans(const short* __restrict__ V,
                                              short* __restrict__ Vt)
{
    __shared__ short t_s[64][72];
    int l0 = blockIdx.x * 64, d0 = blockIdx.y * 64, b = blockIdx.z;
    int t = threadIdx.x;
    const short* src = V + (size_t)b * SEQ * DIM;
    #pragma unroll
    for (int it = 0; it < 2; ++it) {
        int r = (t >> 3) + it * 32, c = (t & 7) * 8;
        *(short8*)&t_s[r][c] = *(const short8*)(src + (size_t)(l0 + r) * DIM + d0 + c);
    }
    __syncthreads();
    short* dst = Vt + (size_t)b * DIM * SEQ;
    #pragma unroll
    for (int it = 0; it < 2; ++it) {
        int r = (t >> 3) + it * 32, c = (t & 7) * 8;
        short8 v;
        #pragma unroll
        for (int j = 0; j < 8; ++j) v[j] = t_s[c + j][r];
        *(short8*)(dst + (size_t)(d0 + r) * SEQ + l0 + c) = v;
    }
}

// ---------------------------------------------------------------- attention v8
// = v4's dbuf structure (8 waves, o[16], 1 full barrier/tile, tile-start DMA)
// + dh-SPLIT QK: each wave computes partial scores over its 256-dim half
// (16 MFMAs, qf[8]) and partials are exchanged as f32 through ss_s using a
// raw s_barrier + lgkmcnt(0) (LDS-only sync; does NOT drain the tile DMA).
// fp add commutativity keeps m/l bit-identical across the dh pair.
__global__ __launch_bounds__(512, 2) void attn_v8(
        const short* __restrict__ Q, const short* __restrict__ K,
        const short* __restrict__ Vt, short* __restrict__ Opart,
        float* __restrict__ Mpart, float* __restrict__ Lpart,
        float scale, const float* __restrict__ scale_ptr,
        const float* __restrict__ gate, int causal, int NC, int ncs)
{
    if (gate && gate[0] == 0.0f) return;
    if (scale_ptr) scale = scale_ptr[0];
    extern __shared__ short lds[];
    short* k_s  = lds;             // [2][32 rows][512 dims] swizzled  64 KB
    short* v_s  = lds + 32768;     // [2][512 d][32 keys] slot16      64 KB
    short* p_s  = lds + 65536;     // [8 waves][16 rows][32]            8 KB
    float* ss_s = (float*)(lds + 69632); // [8 waves][64 lanes][8]     16 KB

    int tid = threadIdx.x, w = tid >> 6, lane = tid & 63;
    int rg = w >> 1, dh = w & 1;
    int lr = lane & 15, lg = lane >> 4;

    int bid = blockIdx.x;
    int c  = bid & (NC - 1);
    int b  = (bid >> ncs) & 1;
    int ip = bid >> (ncs + 1);
    int jj0 = ip, jj1 = 63 - ip;
    int TA = causal ? 2*(ip+1)  : 128;
    int TB = causal ? 2*(64-ip) : 128;
    int Ttot = TA + TB;
    int s0 = (Ttot * c) >> ncs, s1 = (Ttot * (c+1)) >> ncs;

    size_t bofs = (size_t)b * SEQ * DIM;
    size_t vofs = (size_t)b * DIM * SEQ;
    f32x4 zero = {0.f, 0.f, 0.f, 0.f};

    for (int sg = 0; sg < 2; ++sg) {
        int j  = sg ? jj1 : jj0;
        int ta = sg ? (max(s0, TA) - TA) : s0;
        int tb = sg ? (s1 - TA)          : min(s1, TA);
        if (ta >= tb) continue;
        int qw0 = j*64 + rg*16;

        short8 qf[8];                      // own 256-dim half only
        #pragma unroll
        for (int kc = 0; kc < 8; ++kc)
            qf[kc] = *(const short8*)(Q + bofs + (size_t)(qw0 + lr)*DIM
                                      + dh*256 + kc*32 + lg*8);

        f32x4 o[16];
        #pragma unroll
        for (int df = 0; df < 16; ++df) o[df] = zero;
        float mreg[4] = {-1e30f,-1e30f,-1e30f,-1e30f};
        float lreg[4] = {0.f,0.f,0.f,0.f};
        int rowg[4];
        #pragma unroll
        for (int r = 0; r < 4; ++r) rowg[r] = qw0 + lg*4 + r;

        int cur = 0;
        {
            int k0s = ta * KT;
            #pragma unroll
            for (int s4 = 0; s4 < 4; ++s4) {
                int slot = tid + s4*512;
                int row = slot >> 6, cg = slot & 63;
                gload16(K + bofs + (size_t)(k0s + row)*DIM + ((cg ^ (row & 7)) << 3),
                        k_s + slot*8);
                int dpair = slot >> 3, low = slot & 7;
                int d = dpair*2 + (low & 1);
                int kg = (low >> 1) ^ (dpair & 3);
                gload16(Vt + vofs + (size_t)d*SEQ + k0s + kg*8,
                        v_s + slot*8);
            }
        }
        __syncthreads();

        for (int t = ta; t < tb; ++t) {
            int k0 = t * KT;
            if (t + 1 < tb) {              // full-tile prefetch window (v4)
                int k0s = (t + 1) * KT;
                int bo = (cur ^ 1) * 16384;
                #pragma unroll
                for (int s4 = 0; s4 < 4; ++s4) {
                    int slot = tid + s4*512;
                    int row = slot >> 6, cg = slot & 63;
                    gload16(K + bofs + (size_t)(k0s + row)*DIM + ((cg ^ (row & 7)) << 3),
                            k_s + bo + slot*8);
                    int dpair = slot >> 3, low = slot & 7;
                    int d = dpair*2 + (low & 1);
                    int kg = (low >> 1) ^ (dpair & 3);
                    gload16(Vt + vofs + (size_t)d*SEQ + k0s + kg*8,
                            v_s + bo + slot*8);
                }
            }
            // ---- QK^T over OWN 256-dim half (16 MFMA)
            f32x4 ss[2];
            ss[0] = zero; ss[1] = zero;
            const short* kb = k_s + cur*16384;
            #pragma unroll
            for (int kc = 0; kc < 8; ++kc) {
                #pragma unroll
                for (int kf = 0; kf < 2; ++kf) {
                    int row = kf*16 + lr;
                    int dg = dh*32 + kc*4 + lg;
                    short8 kk = *(const short8*)(kb + row*512 + ((dg ^ (row & 7)) << 3));
                    ss[kf] = __builtin_amdgcn_mfma_f32_16x16x32_bf16(qf[kc], kk, ss[kf], 0, 0, 0);
                }
            }
            // ---- exchange partials across dh pair (LDS-only sync, no DMA drain)
            *(f32x4*)(ss_s + w*512 + lane*8)     = ss[0];
            *(f32x4*)(ss_s + w*512 + lane*8 + 4) = ss[1];
            asm volatile("s_waitcnt lgkmcnt(0)" ::: "memory");
            __builtin_amdgcn_s_barrier();
            __builtin_amdgcn_sched_barrier(0);
            f32x4 po0 = *(const f32x4*)(ss_s + (w^1)*512 + lane*8);
            f32x4 po1 = *(const f32x4*)(ss_s + (w^1)*512 + lane*8 + 4);
            // ---- sum + scale + causal mask (commutative add -> pair-identical)
            bool needmask = causal && (k0 + KT - 1 > qw0);
            #pragma unroll
            for (int r = 0; r < 4; ++r) {
                float s0v = (ss[0][r] + po0[r]) * scale;
                float s1v = (ss[1][r] + po1[r]) * scale;
                if (needmask) {
                    if (k0 + lr      > rowg[r]) s0v = -1e30f;
                    if (k0 + 16 + lr > rowg[r]) s1v = -1e30f;
                }
                ss[0][r] = s0v; ss[1][r] = s1v;
            }
            // ---- defer-max (T13) online softmax
            float pm[4];
            bool tg = false;
            #pragma unroll
            for (int r = 0; r < 4; ++r) {
                pm[r] = fmaxf(ss[0][r], ss[1][r]);
                tg |= (pm[r] > mreg[r] + 8.0f);
            }
            if (__any(tg)) {
                #pragma unroll
                for (int r = 0; r < 4; ++r) {
                    float v = pm[r];
                    v = fmaxf(v, __shfl_xor(v, 1));
                    v = fmaxf(v, __shfl_xor(v, 2));
                    v = fmaxf(v, __shfl_xor(v, 4));
                    v = fmaxf(v, __shfl_xor(v, 8));
                    float nm = fmaxf(mreg[r], v);
                    float fr = __expf(mreg[r] - nm);
                    mreg[r] = nm;
                    lreg[r] *= fr;
                    #pragma unroll
                    for (int df = 0; df < 16; ++df) o[df][r] *= fr;
                }
            }
            // ---- P = exp(s - m) -> wave-private LDS -> A-frag
            #pragma unroll
            for (int kf = 0; kf < 2; ++kf) {
                #pragma unroll
                for (int r = 0; r < 4; ++r) {
                    float sv = ss[kf][r];
                    float p = (sv < -1e29f) ? 0.0f : __expf(sv - mreg[r]);
                    lreg[r] += p;
                    int row = lg*4 + r;
                    int oct = kf*2 + (lr >> 3);
                    p_s[w*512 + row*32 + ((oct ^ r ^ (lg & 3)) << 3) + (lr & 7)] = bf16b(p);
                }
            }
            short8 pa = *(const short8*)(p_s + w*512 + lr*32
                         + ((lg ^ (lr & 3) ^ ((lr >> 2) & 3)) << 3));
            // ---- PV (own d-half, 16 MFMA)
            const short* vb = v_s + cur*16384;
            #pragma unroll
            for (int df = 0; df < 16; ++df) {
                int d = dh*256 + df*16 + lr;
                int slot16 = (d >> 1)*8 + (((lg ^ ((d >> 1) & 3)) << 1) | (d & 1));
                short8 vv = *(const short8*)(vb + slot16*8);
                o[df] = __builtin_amdgcn_mfma_f32_16x16x32_bf16(pa, vv, o[df], 0, 0, 0);
            }
            __syncthreads();               // full drain: prefetch + LDS
            cur ^= 1;
        }

        // ---- flush partials for (b, j, c)
        #pragma unroll
        for (int r = 0; r < 4; ++r) {
            float v = lreg[r];
            v += __shfl_xor(v, 1);
            v += __shfl_xor(v, 2);
            v += __shfl_xor(v, 4);
            v += __shfl_xor(v, 8);
            lreg[r] = v;
        }
        int slot = (b*64 + j)*NC + c;
        size_t obase = ((size_t)slot*8 + w) * 4096;
        #pragma unroll
        for (int df = 0; df < 16; ++df) {
            short4v pk;
            #pragma unroll
            for (int r = 0; r < 4; ++r) pk[r] = bf16b(o[df][r]);
            *(short4v*)(Opart + obase + df*256 + lane*4) = pk;
        }
        if (dh == 0 && lr == 0) {
            #pragma unroll
            for (int r = 0; r < 4; ++r) {
                Mpart[slot*64 + rg*16 + lg*4 + r] = mreg[r];
                Lpart[slot*64 + rg*16 + lg*4 + r] = lreg[r];
            }
        }
    }
}

// ---------------------------------------------------------------- merge chunk partials (r5-proven)
__global__ __launch_bounds__(256) void attn_merge(
        const short* __restrict__ Opart, const float* __restrict__ Mpart,
        const float* __restrict__ Lpart, short* __restrict__ attb,
        float* __restrict__ outf, const float* __restrict__ gate,
        int causal, int NC, int ncs)
{
    if (gate && gate[0] == 0.0f) return;
    __shared__ float wts[8][64];
    int j = blockIdx.x, dh = blockIdx.y, b = blockIdx.z;
    int tid = threadIdx.x;
    int ip = (j < 32) ? j : 63 - j;
    int TA = causal ? 2*(ip+1)  : 128;
    int TB = causal ? 2*(64-ip) : 128;
    int Ttot = TA + TB;
    int jstart = (j < 32) ? 0 : TA;
    int jend   = (j < 32) ? TA : Ttot;
    bool val[8];
    for (int c = 0; c < 8; ++c) {
        int sc = (Ttot * c) >> ncs, ec = (Ttot * (c+1)) >> ncs;
        val[c] = (c < NC) && (sc < jend) && (ec > jstart);
    }
    if (tid < 64) {
        float M = -1e30f;
        for (int c = 0; c < NC; ++c)
            if (val[c]) M = fmaxf(M, Mpart[((b*64 + j)*NC + c)*64 + tid]);
        float L = 0.f;
        for (int c = 0; c < NC; ++c)
            if (val[c]) L += Lpart[((b*64 + j)*NC + c)*64 + tid]
                           * __expf(Mpart[((b*64 + j)*NC + c)*64 + tid] - M);
        float invL = 1.0f / L;
        for (int c = 0; c < NC; ++c)
            wts[c][tid] = val[c]
                ? __expf(Mpart[((b*64 + j)*NC + c)*64 + tid] - M) * invL : 0.0f;
    }
    __syncthreads();
    int wv = tid >> 6, lane = tid & 63, lg = lane >> 4, lr = lane & 15;
    int region = wv*2 + dh;
    for (int df = 0; df < 16; ++df) {
        float acc[4] = {0.f, 0.f, 0.f, 0.f};
        for (int c = 0; c < NC; ++c) {
            if (!val[c]) continue;
            size_t idx = ((size_t)((b*64 + j)*NC + c)*8 + region)*4096 + df*256 + lane*4;
            short4v v = *(const short4v*)(Opart + idx);
            #pragma unroll
            for (int r = 0; r < 4; ++r)
                acc[r] += wts[c][wv*16 + lg*4 + r] * bf16f(v[r]);
        }
        #pragma unroll
        for (int r = 0; r < 4; ++r) {
            int row = j*64 + wv*16 + lg*4 + r;
            int d = dh*256 + df*16 + lr;
            size_t oidx = (size_t)b*SEQ*DIM + (size_t)row*DIM + d;
            if (attb) attb[oidx] = bf16b(acc[r]);
            else      outf[oidx] += acc[r];
        }
    }
}

// ---------------------------------------------------------------- last-row scores (bf16 in)
__global__ __launch_bounds__(256) void lastrow_scores(const short* __restrict__ Q,
        const short* __restrict__ K, float* __restrict__ slast)
{
    __shared__ float q_l[DIM];
    int b = blockIdx.y;
    int m = blockIdx.x * 256 + threadIdx.x;
    for (int i = threadIdx.x; i < DIM; i += 256)
        q_l[i] = bf16f(Q[((size_t)b*SEQ + SEQ-1)*DIM + i]);
    __syncthreads();
    const short* kr = K + ((size_t)b*SEQ + m) * DIM;
    float s = 0.f;
    for (int d = 0; d < DIM; d += 8) {
        short8 k8 = *(const short8*)(kr + d);
        #pragma unroll
        for (int j = 0; j < 8; ++j) s += q_l[d + j] * bf16f(k8[j]);
    }
    slast[(size_t)b*SEQ + m] = s * RSQRT_D;
}

// ---------------------------------------------------------------- entropy of last-row softmax
__global__ __launch_bounds__(256) void entropy_kernel(const float* __restrict__ slast,
        float* __restrict__ H)
{
    __shared__ float sm[4];
    int b = blockIdx.x, t = threadIdx.x;
    const float* s = slast + (size_t)b * SEQ;
    float v[16];
    float mx = -1e30f;
    #pragma unroll
    for (int j = 0; j < 16; ++j) { v[j] = s[t + j*256]; mx = fmaxf(mx, v[j]); }
    #pragma unroll
    for (int o = 32; o; o >>= 1) mx = fmaxf(mx, __shfl_xor(mx, o));
    __syncthreads();
    if ((t & 63) == 0) sm[t >> 6] = mx;
    __syncthreads();
    mx = fmaxf(fmaxf(sm[0], sm[1]), fmaxf(sm[2], sm[3]));
    float se = 0.f;
    #pragma unroll
    for (int j = 0; j < 16; ++j) { v[j] = expf(v[j] - mx); se += v[j]; }
    se = blk_sum256(se, sm);
    float inv = 1.0f / se;
    float h = 0.f;
    #pragma unroll
    for (int j = 0; j < 16; ++j) {
        float p = fmaxf(v[j] * inv, 1e-9f);
        h -= p * logf(p);
    }
    h = blk_sum256(h, sm);
    if (t == 0) H[b] = h;
}

// ---------------------------------------------------------------- K mean partials (bf16 in)
__global__ __launch_bounds__(256) void krep_partial(const short* __restrict__ K,
        float* __restrict__ part)
{
    int b = blockIdx.y, j = blockIdx.x, t = threadIdx.x;
    size_t base = ((size_t)b*SEQ + (size_t)j*64) * DIM;
    float s0 = 0.f, s1 = 0.f;
    for (int r = 0; r < 64; ++r) {
        s0 += bf16f(K[base + (size_t)r*DIM + t]);
        s1 += bf16f(K[base + (size_t)r*DIM + t + 256]);
    }
    size_t o = (size_t)(b*64 + j) * DIM;
    part[o + t] = s0; part[o + t + 256] = s1;
}

// ---------------------------------------------------------------- gate scalar kernel
__global__ __launch_bounds__(256) void scalar_kernel(const short* __restrict__ Qb,
        const float* __restrict__ part, const float* __restrict__ Hent,
        float* __restrict__ gsc)
{
    __shared__ float sm[4];
    __shared__ float sims[BATCH];
    int t = threadIdx.x;
    float qv0 = 0.5f*(bf16f(Qb[((size_t)0*SEQ + SEQ-1)*DIM + t])     + bf16f(Qb[((size_t)1*SEQ + SEQ-1)*DIM + t]));
    float qv1 = 0.5f*(bf16f(Qb[((size_t)0*SEQ + SEQ-1)*DIM + t+256]) + bf16f(Qb[((size_t)1*SEQ + SEQ-1)*DIM + t+256]));
    for (int b = 0; b < BATCH; ++b) {
        float k0 = 0.f, k1 = 0.f;
        for (int j = 0; j < 64; ++j) {
            k0 += part[(size_t)(b*64+j)*DIM + t];
            k1 += part[(size_t)(b*64+j)*DIM + t + 256];
        }
        k0 *= (1.0f/SEQ); k1 *= (1.0f/SEQ);
        float num = blk_sum256(qv0*k0 + qv1*k1, sm);
        float qq  = blk_sum256(qv0*qv0 + qv1*qv1, sm);
        float kk  = blk_sum256(k0*k0 + k1*k1, sm);
        if (t == 0) {
            float na = fmaxf(sqrtf(qq), 1e-8f);
            float nb = fmaxf(sqrtf(kk), 1e-8f);
            sims[b] = num / (na * nb);
        }
        __syncthreads();
    }
    if (t == 0) {
        float H0 = Hent[0], H1 = Hent[1];
        float mn = fminf(H0, H1), mx = fmaxf(H0, H1);
        float den = (mx - mn) + 1e-9f;
        float Hm = 0.5f*((H0 - mn)/den + (H1 - mn)/den);
        float T  = 0.6f + (1.6f - 0.6f) * Hm;
        float th = 0.9f - (0.9f - 0.5f) * Hm;
        float s  = 0.5f * (sims[0] + sims[1]);
        gsc[0] = (s >= th) ? 1.0f : 0.0f;
        gsc[1] = 1.0f / (sqrtf((float)DIM) * T);
    }
}

// ---------------------------------------------------------------- launch
extern "C" void kernel_launch(void* const* d_in, const int* in_sizes, int n_in,
                              void* d_out, int out_size, void* d_ws, size_t ws_size,
                              hipStream_t stream)
{
    (void)in_sizes; (void)n_in; (void)out_size;
    const float* x     = (const float*)d_in[0];
    const float* Wq    = (const float*)d_in[1];
    const float* Wk    = (const float*)d_in[2];
    const float* Wv    = (const float*)d_in[3];
    const float* Wp    = (const float*)d_in[4];
    const float* W1    = (const float*)d_in[5];
    const float* b1    = (const float*)d_in[6];
    const float* W2    = (const float*)d_in[7];
    const float* b2    = (const float*)d_in[8];
    const float* gamma = (const float*)d_in[9];
    const float* beta  = (const float*)d_in[10];
    float* out = (float*)d_out;

    const size_t NT = (size_t)NROWS * DIM;   // 4,194,304
    short* bws   = (short*)d_ws;
    short* Qbf   = bws;                      // 4M
    short* Kbf   = Qbf + NT;                 // 4M
    short* Vt    = Kbf + NT;                 // 4M
    short* att   = Vt + NT;                  // 4M (also V pre-transpose temp)
    short* Wcat  = att + NT;                 // 786432
    short* Wpb   = Wcat + 786432;
    short* W1b   = Wpb + 262144;
    short* W2b   = W1b + 1048576;
    float* slast = (float*)(W2b + 1048576);  // 8192
    float* Hent  = slast + 8192;             // 8
    float* kpart = Hent + 8;                 // 65536
    float* gsc   = kpart + 65536;            // 8

    // chunk count: 8 (512 blocks) if workspace allows, else 4
    float* Mpart8 = gsc + 8;
    size_t ml8 = (size_t)128 * 8 * 64;
    short* xn8 = (short*)(Mpart8 + 2*ml8);
    size_t opart8_end = ((size_t)(xn8 - bws)) + (size_t)1024 * 8 * 4096; // shorts
    int NC = (ws_size >= opart8_end * 2 + 1024) ? 8 : 4;
    int ncs = (NC == 8) ? 3 : 2;
    size_t mlsz = (size_t)128 * NC * 64;
    float* Mpart = gsc + 8;
    float* Lpart = Mpart + mlsz;
    short* xn_bf = (short*)(Lpart + mlsz);   // 4M (dead during attention)
    short* h1    = xn_bf + NT;               // FFN hidden (8M half / 16.8M full)
    short* Opart = xn_bf;                    // overlaps xn+h1+beyond

    // full-FFN path needs h1 = NROWS*FF shorts after xn_bf
    size_t ffn_full_end = ((size_t)(h1 - bws) + (size_t)NROWS * FF) * 2;
    int ffn_full = (ws_size >= ffn_full_end + 1024);

    const int ATTN_LDS = 155648;             // 64K k + 64K v + 8K p + 16K ss
    hipFuncSetAttribute((const void*)attn_v8,
                        hipFuncAttributeMaxDynamicSharedMemorySize, ATTN_LDS);

    f2bf_all<<<1536, 256, 0, stream>>>(Wq, Wk, Wv, Wp, W1, W2, Wcat, Wpb, W1b, W2b);

    ln_kernel<<<NROWS/4, 256, 0, stream>>>(x, gamma, beta, xn_bf);

    // fused QKV projection: [8192,512] x [1536,512]^T, routed outputs
    gemm_v2<0><<<dim3(1536/128, NROWS/128), 256, 0, stream>>>(
        xn_bf, Wcat, nullptr, nullptr, nullptr, Qbf, Kbf, att,
        DIM, DIM, DIM, DIM, 0, 0);
    vtrans<<<dim3(SEQ/64, DIM/64, BATCH), 256, 0, stream>>>(att, Vt);
    // xn_bf/h1 dead -> Opart may overwrite them

    attn_v8<<<64*NC, 512, ATTN_LDS, stream>>>(Qbf, Kbf, Vt, Opart, Mpart, Lpart,
                                              RSQRT_D, nullptr, nullptr, 1, NC, ncs);
    attn_merge<<<dim3(64, 2, BATCH), 256, 0, stream>>>(Opart, Mpart, Lpart, att, nullptr,
                                                       nullptr, 1, NC, ncs);

    lastrow_scores<<<dim3(SEQ/256, BATCH), 256, 0, stream>>>(Qbf, Kbf, slast);
    entropy_kernel<<<BATCH, 256, 0, stream>>>(slast, Hent);

    // ctx = x + att @ Wp^T (fp32 into d_out)
    gemm_v2<1><<<dim3(DIM/128, NROWS/128), 256, 0, stream>>>(
        att, Wpb, nullptr, x, out, nullptr, nullptr, nullptr,
        DIM, DIM, DIM, DIM, 0, 0);

    // h = LN(ctx) -> xn_bf (Opart dead after merge)
    ln_kernel<<<NROWS/4, 256, 0, stream>>>(out, gamma, beta, xn_bf);

    if (ffn_full) {
        gemm_v2<2><<<dim3(FF/128, NROWS/128), 256, 0, stream>>>(
            xn_bf, W1b, b1, nullptr, nullptr, h1, nullptr, nullptr,
            DIM, DIM, DIM, FF, 1, 0);
        gemm_v2<3><<<dim3(DIM/128, NROWS/128), 256, 0, stream>>>(
            h1, W2b, b2, nullptr, out, nullptr, nullptr, nullptr,
            FF, FF, FF, DIM, 0, 1);
    } else {
        for (int c = 0; c < 2; ++c) {
            gemm_v2<2><<<dim3(1024/128, NROWS/128), 256, 0, stream>>>(
                xn_bf, W1b + (size_t)c*1024*DIM, b1 + c*1024, nullptr,
                nullptr, h1, nullptr, nullptr,
                DIM, DIM, DIM, 1024, 1, 0);
            gemm_v2<3><<<dim3(DIM/128, NROWS/128), 256, 0, stream>>>(
                h1, W2b + (size_t)c*1024, (c == 0) ? b2 : nullptr, nullptr,
                out, nullptr, nullptr, nullptr,
                1024, 1024, FF, DIM, 0, 1);
        }
    }

    krep_partial<<<dim3(64, BATCH), 256, 0, stream>>>(Kbf, kpart);
    scalar_kernel<<<1, 256, 0, stream>>>(Qbf, kpart, Hent, gsc);

    // gated re-attention (non-causal, temperature), accumulate fp32 into out
    attn_v8<<<64*NC, 512, ATTN_LDS, stream>>>(Qbf, Kbf, Vt, Opart, Mpart, Lpart,
                                              0.0f, gsc + 1, gsc, 0, NC, ncs);
    attn_merge<<<dim3(64, 2, BATCH), 256, 0, stream>>>(Opart, Mpart, Lpart, nullptr, out,
                                                       gsc, 0, NC, ncs);
}

// Round 11
// 340.845 us; speedup vs baseline: 1.1922x; 1.1922x over previous
//
#include <hip/hip_runtime.h>
#include <math.h>

#define BATCH 2
#define SEQ 4096
#define DIM 512
#define FF 2048
#define NROWS (BATCH*SEQ)
#define KT 32
#define RSQRT_D 0.044194173824159216f  /* 1/sqrt(512) */

typedef __attribute__((ext_vector_type(8))) short short8;
typedef __attribute__((ext_vector_type(4))) short short4v;
typedef __attribute__((ext_vector_type(4))) float f32x4;

// ---------------------------------------------------------------- helpers
__device__ __forceinline__ float gelu_f(float v) {
    return 0.5f * v * (1.0f + erff(v * 0.70710678118654752440f));
}
__device__ __forceinline__ short bf16b(float x) {
    union { float f; unsigned u; } c; c.f = x;
    unsigned r = (c.u + 0x7FFFu + ((c.u >> 16) & 1u)) >> 16;
    return (short)r;
}
__device__ __forceinline__ float bf16f(short h) {
    union { unsigned u; float f; } c; c.u = ((unsigned)(unsigned short)h) << 16;
    return c.f;
}
__device__ __forceinline__ void gload16(const void* g, void* l) {
    __builtin_amdgcn_global_load_lds(
        (const __attribute__((address_space(1))) unsigned int*)g,
        (__attribute__((address_space(3))) unsigned int*)l, 16, 0, 0);
}
__device__ __forceinline__ float blk_sum256(float v, volatile float* sm) {
    #pragma unroll
    for (int o = 32; o; o >>= 1) v += __shfl_xor(v, o);
    __syncthreads();
    if ((threadIdx.x & 63) == 0) sm[threadIdx.x >> 6] = v;
    __syncthreads();
    return sm[0] + sm[1] + sm[2] + sm[3];
}

// ---------------------------------------------------------------- all weights f32 -> bf16 (one launch)
__global__ __launch_bounds__(256) void f2bf_all(
        const float* __restrict__ Wq, const float* __restrict__ Wk,
        const float* __restrict__ Wv, const float* __restrict__ Wp,
        const float* __restrict__ W1, const float* __restrict__ W2,
        short* __restrict__ Wcat, short* __restrict__ Wpb,
        short* __restrict__ W1b, short* __restrict__ W2b)
{
    int i = blockIdx.x * 256 + threadIdx.x;    // 8-elem group, total 393216
    const float* src; short* dst; int loc;
    if      (i <  32768) { src = Wq; dst = Wcat;          loc = i; }
    else if (i <  65536) { src = Wk; dst = Wcat + 262144; loc = i - 32768; }
    else if (i <  98304) { src = Wv; dst = Wcat + 524288; loc = i - 65536; }
    else if (i < 131072) { src = Wp; dst = Wpb;           loc = i - 98304; }
    else if (i < 262144) { src = W1; dst = W1b;           loc = i - 131072; }
    else                 { src = W2; dst = W2b;           loc = i - 262144; }
    const float4* p = (const float4*)(src + (size_t)loc * 8);
    float4 a = p[0], b = p[1];
    short8 r;
    r[0]=bf16b(a.x); r[1]=bf16b(a.y); r[2]=bf16b(a.z); r[3]=bf16b(a.w);
    r[4]=bf16b(b.x); r[5]=bf16b(b.y); r[6]=bf16b(b.z); r[7]=bf16b(b.w);
    *(short8*)(dst + (size_t)loc * 8) = r;
}

// ---------------------------------------------------------------- layernorm (f32 in, bf16 out)
__global__ __launch_bounds__(256) void ln_kernel(const float* __restrict__ x,
        const float* __restrict__ g, const float* __restrict__ be,
        short* __restrict__ o)
{
    int row  = blockIdx.x * 4 + (threadIdx.x >> 6);
    int lane = threadIdx.x & 63;
    const float4* xr = (const float4*)(x + (size_t)row * DIM);
    float4 v0 = xr[lane*2], v1 = xr[lane*2+1];
    float s = v0.x+v0.y+v0.z+v0.w + v1.x+v1.y+v1.z+v1.w;
    #pragma unroll
    for (int off = 32; off; off >>= 1) s += __shfl_xor(s, off);
    float mu = s * (1.0f/DIM);
    float d[8] = {v0.x-mu, v0.y-mu, v0.z-mu, v0.w-mu, v1.x-mu, v1.y-mu, v1.z-mu, v1.w-mu};
    float q = 0.f;
    #pragma unroll
    for (int j = 0; j < 8; ++j) q += d[j]*d[j];
    #pragma unroll
    for (int off = 32; off; off >>= 1) q += __shfl_xor(q, off);
    float rs = rsqrtf(q * (1.0f/DIM) + 1e-5f);
    const float4* g4 = (const float4*)g;
    const float4* b4 = (const float4*)be;
    float4 ga = g4[lane*2], gb = g4[lane*2+1];
    float4 ba = b4[lane*2], bb = b4[lane*2+1];
    float gv[8] = {ga.x,ga.y,ga.z,ga.w, gb.x,gb.y,gb.z,gb.w};
    float bv[8] = {ba.x,ba.y,ba.z,ba.w, bb.x,bb.y,bb.z,bb.w};
    short8 r;
    #pragma unroll
    for (int j = 0; j < 8; ++j) r[j] = bf16b(d[j]*rs*gv[j] + bv[j]);
    *(short8*)(o + (size_t)row * DIM + lane*8) = r;
}

// ---------------------------------------------------------------- bf16 MFMA GEMM v3
// TM x 128 tile (TM = 128 or 64), BK=32, 256 thr (2x2 waves), dbuf LDS,
// prefetch-at-top + single barrier per K-step (r5-proven schedule).
// TM=64 halves acc (32 AGPR) and doubles grid for small-N GEMMs -> >=2 blocks/CU.
template<int TM, int TAG>
__global__ __launch_bounds__(256) void gemm_v3(
        const short* __restrict__ A, const short* __restrict__ W,
        const float* __restrict__ bias, const float* __restrict__ res,
        float* __restrict__ Cf, short* __restrict__ Cb,
        short* __restrict__ CbK, short* __restrict__ CbV,
        int K, int sa, int sw, int sc, int act, int accum)
{
    constexpr int MI = TM / 32;           // acc fragments per wave in M
    __shared__ short As[2][TM*32];
    __shared__ short Ws[2][4096];
    int tid = threadIdx.x;
    int m0 = blockIdx.y * TM, n0 = blockIdx.x * 128;
    int w = tid >> 6, lane = tid & 63;
    int wr = (w >> 1) * (TM/2), wc = (w & 1) * 64;
    int lr = lane & 15, lg = lane >> 4;
    int srow = tid >> 2, skoff = (tid & 3) * 8;
    const short* Ab = A + (size_t)(m0 + srow) * sa + skoff;
    const short* Wb = W + (size_t)(n0 + srow) * sw + skoff;

    #define STAGE_G(buf, kk) do { \
        gload16(Ab + (kk),                    As[buf] + tid*8); \
        if constexpr (TM == 128) \
            gload16(Ab + (size_t)64*sa + (kk), As[buf] + 2048 + tid*8); \
        gload16(Wb + (kk),                    Ws[buf] + tid*8); \
        gload16(Wb + (size_t)64*sw + (kk),    Ws[buf] + 2048 + tid*8); } while(0)

    f32x4 acc[MI][4];
    f32x4 zero = {0.f, 0.f, 0.f, 0.f};
    #pragma unroll
    for (int i = 0; i < MI; ++i)
        #pragma unroll
        for (int j = 0; j < 4; ++j) acc[i][j] = zero;

    STAGE_G(0, 0);
    __syncthreads();
    int cur = 0;
    for (int k0 = 0; k0 < K; k0 += 32) {
        if (k0 + 32 < K) STAGE_G(cur ^ 1, k0 + 32);
        short8 a[MI], b[4];
        #pragma unroll
        for (int i = 0; i < MI; ++i) a[i] = *(const short8*)(As[cur] + (wr + i*16 + lr)*32 + lg*8);
        #pragma unroll
        for (int j = 0; j < 4; ++j) b[j] = *(const short8*)(Ws[cur] + (wc + j*16 + lr)*32 + lg*8);
        #pragma unroll
        for (int i = 0; i < MI; ++i)
            #pragma unroll
            for (int j = 0; j < 4; ++j)
                acc[i][j] = __builtin_amdgcn_mfma_f32_16x16x32_bf16(a[i], b[j], acc[i][j], 0, 0, 0);
        __syncthreads();
        cur ^= 1;
    }
    #undef STAGE_G

    #pragma unroll
    for (int i = 0; i < MI; ++i) {
        #pragma unroll
        for (int r = 0; r < 4; ++r) {
            size_t m = (size_t)m0 + wr + i*16 + lg*4 + r;
            #pragma unroll
            for (int j = 0; j < 4; ++j) {
                int n = n0 + wc + j*16 + lr;
                float v = acc[i][j][r];
                if (bias) v += bias[n];
                if (act)  v = gelu_f(v);
                if (CbK) {
                    int seg = n >> 9, nl = n & 511;
                    short* dst = (seg == 0) ? Cb : (seg == 1) ? CbK : CbV;
                    dst[m * 512 + nl] = bf16b(v);
                } else {
                    if (res) v += res[m * sc + n];
                    size_t idx = m * sc + n;
                    if (Cf) { if (accum) Cf[idx] += v; else Cf[idx] = v; }
                    if (Cb) Cb[idx] = bf16b(v);
                }
            }
        }
    }
}

// ---------------------------------------------------------------- bf16 tile transpose V[b][l][d] -> Vt[b][d][l]
__global__ __launch_bounds__(256) void vtrans(const short* __restrict__ V,
                                              short* __restrict__ Vt)
{
    __shared__ short t_s[64][72];
    int l0 = blockIdx.x * 64, d0 = blockIdx.y * 64, b = blockIdx.z;
    int t = threadIdx.x;
    const short* src = V + (size_t)b * SEQ * DIM;
    #pragma unroll
    for (int it = 0; it < 2; ++it) {
        int r = (t >> 3) + it * 32, c = (t & 7) * 8;
        *(short8*)&t_s[r][c] = *(const short8*)(src + (size_t)(l0 + r) * DIM + d0 + c);
    }
    __syncthreads();
    short* dst = Vt + (size_t)b * DIM * SEQ;
    #pragma unroll
    for (int it = 0; it < 2; ++it) {
        int r = (t >> 3) + it * 32, c = (t & 7) * 8;
        short8 v;
        #pragma unroll
        for (int j = 0; j < 8; ++j) v[j] = t_s[c + j][r];
        *(short8*)(dst + (size_t)(d0 + r) * SEQ + l0 + c) = v;
    }
}

// ---------------------------------------------------------------- attention v8 (r10-proven, byte-identical)
__global__ __launch_bounds__(512, 2) void attn_v8(
        const short* __restrict__ Q, const short* __restrict__ K,
        const short* __restrict__ Vt, short* __restrict__ Opart,
        float* __restrict__ Mpart, float* __restrict__ Lpart,
        float scale, const float* __restrict__ scale_ptr,
        const float* __restrict__ gate, int causal, int NC, int ncs)
{
    if (gate && gate[0] == 0.0f) return;
    if (scale_ptr) scale = scale_ptr[0];
    extern __shared__ short lds[];
    short* k_s  = lds;             // [2][32 rows][512 dims] swizzled  64 KB
    short* v_s  = lds + 32768;     // [2][512 d][32 keys] slot16      64 KB
    short* p_s  = lds + 65536;     // [8 waves][16 rows][32]            8 KB
    float* ss_s = (float*)(lds + 69632); // [8 waves][64 lanes][8]     16 KB

    int tid = threadIdx.x, w = tid >> 6, lane = tid & 63;
    int rg = w >> 1, dh = w & 1;
    int lr = lane & 15, lg = lane >> 4;

    int bid = blockIdx.x;
    int c  = bid & (NC - 1);
    int b  = (bid >> ncs) & 1;
    int ip = bid >> (ncs + 1);
    int jj0 = ip, jj1 = 63 - ip;
    int TA = causal ? 2*(ip+1)  : 128;
    int TB = causal ? 2*(64-ip) : 128;
    int Ttot = TA + TB;
    int s0 = (Ttot * c) >> ncs, s1 = (Ttot * (c+1)) >> ncs;

    size_t bofs = (size_t)b * SEQ * DIM;
    size_t vofs = (size_t)b * DIM * SEQ;
    f32x4 zero = {0.f, 0.f, 0.f, 0.f};

    for (int sg = 0; sg < 2; ++sg) {
        int j  = sg ? jj1 : jj0;
        int ta = sg ? (max(s0, TA) - TA) : s0;
        int tb = sg ? (s1 - TA)          : min(s1, TA);
        if (ta >= tb) continue;
        int qw0 = j*64 + rg*16;

        short8 qf[8];                      // own 256-dim half only
        #pragma unroll
        for (int kc = 0; kc < 8; ++kc)
            qf[kc] = *(const short8*)(Q + bofs + (size_t)(qw0 + lr)*DIM
                                      + dh*256 + kc*32 + lg*8);

        f32x4 o[16];
        #pragma unroll
        for (int df = 0; df < 16; ++df) o[df] = zero;
        float mreg[4] = {-1e30f,-1e30f,-1e30f,-1e30f};
        float lreg[4] = {0.f,0.f,0.f,0.f};
        int rowg[4];
        #pragma unroll
        for (int r = 0; r < 4; ++r) rowg[r] = qw0 + lg*4 + r;

        int cur = 0;
        {
            int k0s = ta * KT;
            #pragma unroll
            for (int s4 = 0; s4 < 4; ++s4) {
                int slot = tid + s4*512;
                int row = slot >> 6, cg = slot & 63;
                gload16(K + bofs + (size_t)(k0s + row)*DIM + ((cg ^ (row & 7)) << 3),
                        k_s + slot*8);
                int dpair = slot >> 3, low = slot & 7;
                int d = dpair*2 + (low & 1);
                int kg = (low >> 1) ^ (dpair & 3);
                gload16(Vt + vofs + (size_t)d*SEQ + k0s + kg*8,
                        v_s + slot*8);
            }
        }
        __syncthreads();

        for (int t = ta; t < tb; ++t) {
            int k0 = t * KT;
            if (t + 1 < tb) {              // full-tile prefetch window
                int k0s = (t + 1) * KT;
                int bo = (cur ^ 1) * 16384;
                #pragma unroll
                for (int s4 = 0; s4 < 4; ++s4) {
                    int slot = tid + s4*512;
                    int row = slot >> 6, cg = slot & 63;
                    gload16(K + bofs + (size_t)(k0s + row)*DIM + ((cg ^ (row & 7)) << 3),
                            k_s + bo + slot*8);
                    int dpair = slot >> 3, low = slot & 7;
                    int d = dpair*2 + (low & 1);
                    int kg = (low >> 1) ^ (dpair & 3);
                    gload16(Vt + vofs + (size_t)d*SEQ + k0s + kg*8,
                            v_s + bo + slot*8);
                }
            }
            // ---- QK^T over OWN 256-dim half (16 MFMA)
            f32x4 ss[2];
            ss[0] = zero; ss[1] = zero;
            const short* kb = k_s + cur*16384;
            #pragma unroll
            for (int kc = 0; kc < 8; ++kc) {
                #pragma unroll
                for (int kf = 0; kf < 2; ++kf) {
                    int row = kf*16 + lr;
                    int dg = dh*32 + kc*4 + lg;
                    short8 kk = *(const short8*)(kb + row*512 + ((dg ^ (row & 7)) << 3));
                    ss[kf] = __builtin_amdgcn_mfma_f32_16x16x32_bf16(qf[kc], kk, ss[kf], 0, 0, 0);
                }
            }
            // ---- exchange partials across dh pair (LDS-only sync, no DMA drain)
            *(f32x4*)(ss_s + w*512 + lane*8)     = ss[0];
            *(f32x4*)(ss_s + w*512 + lane*8 + 4) = ss[1];
            asm volatile("s_waitcnt lgkmcnt(0)" ::: "memory");
            __builtin_amdgcn_s_barrier();
            __builtin_amdgcn_sched_barrier(0);
            f32x4 po0 = *(const f32x4*)(ss_s + (w^1)*512 + lane*8);
            f32x4 po1 = *(const f32x4*)(ss_s + (w^1)*512 + lane*8 + 4);
            // ---- sum + scale + causal mask (commutative add -> pair-identical)
            bool needmask = causal && (k0 + KT - 1 > qw0);
            #pragma unroll
            for (int r = 0; r < 4; ++r) {
                float s0v = (ss[0][r] + po0[r]) * scale;
                float s1v = (ss[1][r] + po1[r]) * scale;
                if (needmask) {
                    if (k0 + lr      > rowg[r]) s0v = -1e30f;
                    if (k0 + 16 + lr > rowg[r]) s1v = -1e30f;
                }
                ss[0][r] = s0v; ss[1][r] = s1v;
            }
            // ---- defer-max (T13) online softmax
            float pm[4];
            bool tg = false;
            #pragma unroll
            for (int r = 0; r < 4; ++r) {
                pm[r] = fmaxf(ss[0][r], ss[1][r]);
                tg |= (pm[r] > mreg[r] + 8.0f);
            }
            if (__any(tg)) {
                #pragma unroll
                for (int r = 0; r < 4; ++r) {
                    float v = pm[r];
                    v = fmaxf(v, __shfl_xor(v, 1));
                    v = fmaxf(v, __shfl_xor(v, 2));
                    v = fmaxf(v, __shfl_xor(v, 4));
                    v = fmaxf(v, __shfl_xor(v, 8));
                    float nm = fmaxf(mreg[r], v);
                    float fr = __expf(mreg[r] - nm);
                    mreg[r] = nm;
                    lreg[r] *= fr;
                    #pragma unroll
                    for (int df = 0; df < 16; ++df) o[df][r] *= fr;
                }
            }
            // ---- P = exp(s - m) -> wave-private LDS -> A-frag
            #pragma unroll
            for (int kf = 0; kf < 2; ++kf) {
                #pragma unroll
                for (int r = 0; r < 4; ++r) {
                    float sv = ss[kf][r];
                    float p = (sv < -1e29f) ? 0.0f : __expf(sv - mreg[r]);
                    lreg[r] += p;
                    int row = lg*4 + r;
                    int oct = kf*2 + (lr >> 3);
                    p_s[w*512 + row*32 + ((oct ^ r ^ (lg & 3)) << 3) + (lr & 7)] = bf16b(p);
                }
            }
            short8 pa = *(const short8*)(p_s + w*512 + lr*32
                         + ((lg ^ (lr & 3) ^ ((lr >> 2) & 3)) << 3));
            // ---- PV (own d-half, 16 MFMA)
            const short* vb = v_s + cur*16384;
            #pragma unroll
            for (int df = 0; df < 16; ++df) {
                int d = dh*256 + df*16 + lr;
                int slot16 = (d >> 1)*8 + (((lg ^ ((d >> 1) & 3)) << 1) | (d & 1));
                short8 vv = *(const short8*)(vb + slot16*8);
                o[df] = __builtin_amdgcn_mfma_f32_16x16x32_bf16(pa, vv, o[df], 0, 0, 0);
            }
            __syncthreads();               // full drain: prefetch + LDS
            cur ^= 1;
        }

        // ---- flush partials for (b, j, c)
        #pragma unroll
        for (int r = 0; r < 4; ++r) {
            float v = lreg[r];
            v += __shfl_xor(v, 1);
            v += __shfl_xor(v, 2);
            v += __shfl_xor(v, 4);
            v += __shfl_xor(v, 8);
            lreg[r] = v;
        }
        int slot = (b*64 + j)*NC + c;
        size_t obase = ((size_t)slot*8 + w) * 4096;
        #pragma unroll
        for (int df = 0; df < 16; ++df) {
            short4v pk;
            #pragma unroll
            for (int r = 0; r < 4; ++r) pk[r] = bf16b(o[df][r]);
            *(short4v*)(Opart + obase + df*256 + lane*4) = pk;
        }
        if (dh == 0 && lr == 0) {
            #pragma unroll
            for (int r = 0; r < 4; ++r) {
                Mpart[slot*64 + rg*16 + lg*4 + r] = mreg[r];
                Lpart[slot*64 + rg*16 + lg*4 + r] = lreg[r];
            }
        }
    }
}

// ---------------------------------------------------------------- merge chunk partials
__global__ __launch_bounds__(256) void attn_merge(
        const short* __restrict__ Opart, const float* __restrict__ Mpart,
        const float* __restrict__ Lpart, short* __restrict__ attb,
        float* __restrict__ outf, const float* __restrict__ gate,
        int causal, int NC, int ncs)
{
    if (gate && gate[0] == 0.0f) return;
    __shared__ float wts[8][64];
    int j = blockIdx.x, dh = blockIdx.y, b = blockIdx.z;
    int tid = threadIdx.x;
    int ip = (j < 32) ? j : 63 - j;
    int TA = causal ? 2*(ip+1)  : 128;
    int TB = causal ? 2*(64-ip) : 128;
    int Ttot = TA + TB;
    int jstart = (j < 32) ? 0 : TA;
    int jend   = (j < 32) ? TA : Ttot;
    bool val[8];
    for (int c = 0; c < 8; ++c) {
        int sc = (Ttot * c) >> ncs, ec = (Ttot * (c+1)) >> ncs;
        val[c] = (c < NC) && (sc < jend) && (ec > jstart);
    }
    if (tid < 64) {
        float M = -1e30f;
        for (int c = 0; c < NC; ++c)
            if (val[c]) M = fmaxf(M, Mpart[((b*64 + j)*NC + c)*64 + tid]);
        float L = 0.f;
        for (int c = 0; c < NC; ++c)
            if (val[c]) L += Lpart[((b*64 + j)*NC + c)*64 + tid]
                           * __expf(Mpart[((b*64 + j)*NC + c)*64 + tid] - M);
        float invL = 1.0f / L;
        for (int c = 0; c < NC; ++c)
            wts[c][tid] = val[c]
                ? __expf(Mpart[((b*64 + j)*NC + c)*64 + tid] - M) * invL : 0.0f;
    }
    __syncthreads();
    int wv = tid >> 6, lane = tid & 63, lg = lane >> 4, lr = lane & 15;
    int region = wv*2 + dh;
    for (int df = 0; df < 16; ++df) {
        float acc[4] = {0.f, 0.f, 0.f, 0.f};
        for (int c = 0; c < NC; ++c) {
            if (!val[c]) continue;
            size_t idx = ((size_t)((b*64 + j)*NC + c)*8 + region)*4096 + df*256 + lane*4;
            short4v v = *(const short4v*)(Opart + idx);
            #pragma unroll
            for (int r = 0; r < 4; ++r)
                acc[r] += wts[c][wv*16 + lg*4 + r] * bf16f(v[r]);
        }
        #pragma unroll
        for (int r = 0; r < 4; ++r) {
            int row = j*64 + wv*16 + lg*4 + r;
            int d = dh*256 + df*16 + lr;
            size_t oidx = (size_t)b*SEQ*DIM + (size_t)row*DIM + d;
            if (attb) attb[oidx] = bf16b(acc[r]);
            else      outf[oidx] += acc[r];
        }
    }
}

// ---------------------------------------------------------------- last-row scores (bf16 in)
__global__ __launch_bounds__(256) void lastrow_scores(const short* __restrict__ Q,
        const short* __restrict__ K, float* __restrict__ slast)
{
    __shared__ float q_l[DIM];
    int b = blockIdx.y;
    int m = blockIdx.x * 256 + threadIdx.x;
    for (int i = threadIdx.x; i < DIM; i += 256)
        q_l[i] = bf16f(Q[((size_t)b*SEQ + SEQ-1)*DIM + i]);
    __syncthreads();
    const short* kr = K + ((size_t)b*SEQ + m) * DIM;
    float s = 0.f;
    for (int d = 0; d < DIM; d += 8) {
        short8 k8 = *(const short8*)(kr + d);
        #pragma unroll
        for (int j = 0; j < 8; ++j) s += q_l[d + j] * bf16f(k8[j]);
    }
    slast[(size_t)b*SEQ + m] = s * RSQRT_D;
}

// ---------------------------------------------------------------- entropy of last-row softmax
__global__ __launch_bounds__(256) void entropy_kernel(const float* __restrict__ slast,
        float* __restrict__ H)
{
    __shared__ float sm[4];
    int b = blockIdx.x, t = threadIdx.x;
    const float* s = slast + (size_t)b * SEQ;
    float v[16];
    float mx = -1e30f;
    #pragma unroll
    for (int j = 0; j < 16; ++j) { v[j] = s[t + j*256]; mx = fmaxf(mx, v[j]); }
    #pragma unroll
    for (int o = 32; o; o >>= 1) mx = fmaxf(mx, __shfl_xor(mx, o));
    __syncthreads();
    if ((t & 63) == 0) sm[t >> 6] = mx;
    __syncthreads();
    mx = fmaxf(fmaxf(sm[0], sm[1]), fmaxf(sm[2], sm[3]));
    float se = 0.f;
    #pragma unroll
    for (int j = 0; j < 16; ++j) { v[j] = expf(v[j] - mx); se += v[j]; }
    se = blk_sum256(se, sm);
    float inv = 1.0f / se;
    float h = 0.f;
    #pragma unroll
    for (int j = 0; j < 16; ++j) {
        float p = fmaxf(v[j] * inv, 1e-9f);
        h -= p * logf(p);
    }
    h = blk_sum256(h, sm);
    if (t == 0) H[b] = h;
}

// ---------------------------------------------------------------- K mean partials (bf16 in)
__global__ __launch_bounds__(256) void krep_partial(const short* __restrict__ K,
        float* __restrict__ part)
{
    int b = blockIdx.y, j = blockIdx.x, t = threadIdx.x;
    size_t base = ((size_t)b*SEQ + (size_t)j*64) * DIM;
    float s0 = 0.f, s1 = 0.f;
    for (int r = 0; r < 64; ++r) {
        s0 += bf16f(K[base + (size_t)r*DIM + t]);
        s1 += bf16f(K[base + (size_t)r*DIM + t + 256]);
    }
    size_t o = (size_t)(b*64 + j) * DIM;
    part[o + t] = s0; part[o + t + 256] = s1;
}

// ---------------------------------------------------------------- gate scalar kernel
__global__ __launch_bounds__(256) void scalar_kernel(const short* __restrict__ Qb,
        const float* __restrict__ part, const float* __restrict__ Hent,
        float* __restrict__ gsc)
{
    __shared__ float sm[4];
    __shared__ float sims[BATCH];
    int t = threadIdx.x;
    float qv0 = 0.5f*(bf16f(Qb[((size_t)0*SEQ + SEQ-1)*DIM + t])     + bf16f(Qb[((size_t)1*SEQ + SEQ-1)*DIM + t]));
    float qv1 = 0.5f*(bf16f(Qb[((size_t)0*SEQ + SEQ-1)*DIM + t+256]) + bf16f(Qb[((size_t)1*SEQ + SEQ-1)*DIM + t+256]));
    for (int b = 0; b < BATCH; ++b) {
        float k0 = 0.f, k1 = 0.f;
        for (int j = 0; j < 64; ++j) {
            k0 += part[(size_t)(b*64+j)*DIM + t];
            k1 += part[(size_t)(b*64+j)*DIM + t + 256];
        }
        k0 *= (1.0f/SEQ); k1 *= (1.0f/SEQ);
        float num = blk_sum256(qv0*k0 + qv1*k1, sm);
        float qq  = blk_sum256(qv0*qv0 + qv1*qv1, sm);
        float kk  = blk_sum256(k0*k0 + k1*k1, sm);
        if (t == 0) {
            float na = fmaxf(sqrtf(qq), 1e-8f);
            float nb = fmaxf(sqrtf(kk), 1e-8f);
            sims[b] = num / (na * nb);
        }
        __syncthreads();
    }
    if (t == 0) {
        float H0 = Hent[0], H1 = Hent[1];
        float mn = fminf(H0, H1), mx = fmaxf(H0, H1);
        float den = (mx - mn) + 1e-9f;
        float Hm = 0.5f*((H0 - mn)/den + (H1 - mn)/den);
        float T  = 0.6f + (1.6f - 0.6f) * Hm;
        float th = 0.9f - (0.9f - 0.5f) * Hm;
        float s  = 0.5f * (sims[0] + sims[1]);
        gsc[0] = (s >= th) ? 1.0f : 0.0f;
        gsc[1] = 1.0f / (sqrtf((float)DIM) * T);
    }
}

// ---------------------------------------------------------------- launch
extern "C" void kernel_launch(void* const* d_in, const int* in_sizes, int n_in,
                              void* d_out, int out_size, void* d_ws, size_t ws_size,
                              hipStream_t stream)
{
    (void)in_sizes; (void)n_in; (void)out_size;
    const float* x     = (const float*)d_in[0];
    const float* Wq    = (const float*)d_in[1];
    const float* Wk    = (const float*)d_in[2];
    const float* Wv    = (const float*)d_in[3];
    const float* Wp    = (const float*)d_in[4];
    const float* W1    = (const float*)d_in[5];
    const float* b1    = (const float*)d_in[6];
    const float* W2    = (const float*)d_in[7];
    const float* b2    = (const float*)d_in[8];
    const float* gamma = (const float*)d_in[9];
    const float* beta  = (const float*)d_in[10];
    float* out = (float*)d_out;

    const size_t NT = (size_t)NROWS * DIM;   // 4,194,304
    short* bws   = (short*)d_ws;
    short* Qbf   = bws;                      // 4M
    short* Kbf   = Qbf + NT;                 // 4M
    short* Vt    = Kbf + NT;                 // 4M
    short* att   = Vt + NT;                  // 4M (also V pre-transpose temp)
    short* Wcat  = att + NT;                 // 786432
    short* Wpb   = Wcat + 786432;
    short* W1b   = Wpb + 262144;
    short* W2b   = W1b + 1048576;
    float* slast = (float*)(W2b + 1048576);  // 8192
    float* Hent  = slast + 8192;             // 8
    float* kpart = Hent + 8;                 // 65536
    float* gsc   = kpart + 65536;            // 8

    const int NC = 4, ncs = 2;               // r5/r8 showed attn NC-invariant; NC=4 halves merge traffic
    size_t mlsz = (size_t)128 * NC * 64;
    float* Mpart = gsc + 8;
    float* Lpart = Mpart + mlsz;
    short* xn_bf = (short*)(Lpart + mlsz);   // 4M (dead during attention)
    short* h1    = xn_bf + NT;               // FFN hidden (8M half / 16.8M full)
    short* Opart = xn_bf;                    // overlaps xn+h1+beyond

    // full-FFN path needs h1 = NROWS*FF shorts after xn_bf
    size_t ffn_full_end = ((size_t)(h1 - bws) + (size_t)NROWS * FF) * 2;
    int ffn_full = (ws_size >= ffn_full_end + 1024);

    const int ATTN_LDS = 155648;             // 64K k + 64K v + 8K p + 16K ss
    hipFuncSetAttribute((const void*)attn_v8,
                        hipFuncAttributeMaxDynamicSharedMemorySize, ATTN_LDS);

    f2bf_all<<<1536, 256, 0, stream>>>(Wq, Wk, Wv, Wp, W1, W2, Wcat, Wpb, W1b, W2b);

    ln_kernel<<<NROWS/4, 256, 0, stream>>>(x, gamma, beta, xn_bf);

    // fused QKV projection: [8192,512] x [1536,512]^T, routed outputs
    gemm_v3<128,0><<<dim3(1536/128, NROWS/128), 256, 0, stream>>>(
        xn_bf, Wcat, nullptr, nullptr, nullptr, Qbf, Kbf, att,
        DIM, DIM, DIM, DIM, 0, 0);
    vtrans<<<dim3(SEQ/64, DIM/64, BATCH), 256, 0, stream>>>(att, Vt);
    // xn_bf/h1 dead -> Opart may overwrite them

    attn_v8<<<64*NC, 512, ATTN_LDS, stream>>>(Qbf, Kbf, Vt, Opart, Mpart, Lpart,
                                              RSQRT_D, nullptr, nullptr, 1, NC, ncs);
    attn_merge<<<dim3(64, 2, BATCH), 256, 0, stream>>>(Opart, Mpart, Lpart, att, nullptr,
                                                       nullptr, 1, NC, ncs);

    lastrow_scores<<<dim3(SEQ/256, BATCH), 256, 0, stream>>>(Qbf, Kbf, slast);
    entropy_kernel<<<BATCH, 256, 0, stream>>>(slast, Hent);

    // ctx = x + att @ Wp^T (fp32 into d_out) -- TM=64: grid (4,128)=512 blocks
    gemm_v3<64,1><<<dim3(DIM/128, NROWS/64), 256, 0, stream>>>(
        att, Wpb, nullptr, x, out, nullptr, nullptr, nullptr,
        DIM, DIM, DIM, DIM, 0, 0);

    // h = LN(ctx) -> xn_bf (Opart dead after merge)
    ln_kernel<<<NROWS/4, 256, 0, stream>>>(out, gamma, beta, xn_bf);

    if (ffn_full) {
        gemm_v3<128,2><<<dim3(FF/128, NROWS/128), 256, 0, stream>>>(
            xn_bf, W1b, b1, nullptr, nullptr, h1, nullptr, nullptr,
            DIM, DIM, DIM, FF, 1, 0);
        // W2: TM=64 -> 512 blocks, 2+ blocks/CU (was 256 = 1/CU, fully exposed)
        gemm_v3<64,3><<<dim3(DIM/128, NROWS/64), 256, 0, stream>>>(
            h1, W2b, b2, nullptr, out, nullptr, nullptr, nullptr,
            FF, FF, FF, DIM, 0, 1);
    } else {
        for (int c = 0; c < 2; ++c) {
            gemm_v3<128,2><<<dim3(1024/128, NROWS/128), 256, 0, stream>>>(
                xn_bf, W1b + (size_t)c*1024*DIM, b1 + c*1024, nullptr,
                nullptr, h1, nullptr, nullptr,
                DIM, DIM, DIM, 1024, 1, 0);
            gemm_v3<64,3><<<dim3(DIM/128, NROWS/64), 256, 0, stream>>>(
                h1, W2b + (size_t)c*1024, (c == 0) ? b2 : nullptr, nullptr,
                out, nullptr, nullptr, nullptr,
                1024, 1024, FF, DIM, 0, 1);
        }
    }

    krep_partial<<<dim3(64, BATCH), 256, 0, stream>>>(Kbf, kpart);
    scalar_kernel<<<1, 256, 0, stream>>>(Qbf, kpart, Hent, gsc);

    // gated re-attention (non-causal, temperature), accumulate fp32 into out
    attn_v8<<<64*NC, 512, ATTN_LDS, stream>>>(Qbf, Kbf, Vt, Opart, Mpart, Lpart,
                                              0.0f, gsc + 1, gsc, 0, NC, ncs);
    attn_merge<<<dim3(64, 2, BATCH), 256, 0, stream>>>(Opart, Mpart, Lpart, nullptr, out,
                                                       gsc, 0, NC, ncs);
}

// Round 12
// 337.317 us; speedup vs baseline: 1.2047x; 1.0105x over previous
//
#include <hip/hip_runtime.h>
#include <math.h>

#define BATCH 2
#define SEQ 4096
#define DIM 512
#define FF 2048
#define NROWS (BATCH*SEQ)
#define KT 32
#define RSQRT_D 0.044194173824159216f  /* 1/sqrt(512) */

typedef __attribute__((ext_vector_type(8))) short short8;
typedef __attribute__((ext_vector_type(4))) short short4v;
typedef __attribute__((ext_vector_type(4))) float f32x4;

// ---------------------------------------------------------------- helpers
__device__ __forceinline__ float gelu_f(float v) {
    return 0.5f * v * (1.0f + erff(v * 0.70710678118654752440f));
}
__device__ __forceinline__ short bf16b(float x) {
    union { float f; unsigned u; } c; c.f = x;
    unsigned r = (c.u + 0x7FFFu + ((c.u >> 16) & 1u)) >> 16;
    return (short)r;
}
__device__ __forceinline__ float bf16f(short h) {
    union { unsigned u; float f; } c; c.u = ((unsigned)(unsigned short)h) << 16;
    return c.f;
}
__device__ __forceinline__ void gload16(const void* g, void* l) {
    __builtin_amdgcn_global_load_lds(
        (const __attribute__((address_space(1))) unsigned int*)g,
        (__attribute__((address_space(3))) unsigned int*)l, 16, 0, 0);
}
__device__ __forceinline__ float blk_sum256(float v, volatile float* sm) {
    #pragma unroll
    for (int o = 32; o; o >>= 1) v += __shfl_xor(v, o);
    __syncthreads();
    if ((threadIdx.x & 63) == 0) sm[threadIdx.x >> 6] = v;
    __syncthreads();
    return sm[0] + sm[1] + sm[2] + sm[3];
}

// ---------------------------------------------------------------- all weights f32 -> bf16 (one launch)
__global__ __launch_bounds__(256) void f2bf_all(
        const float* __restrict__ Wq, const float* __restrict__ Wk,
        const float* __restrict__ Wv, const float* __restrict__ Wp,
        const float* __restrict__ W1, const float* __restrict__ W2,
        short* __restrict__ Wcat, short* __restrict__ Wpb,
        short* __restrict__ W1b, short* __restrict__ W2b)
{
    int i = blockIdx.x * 256 + threadIdx.x;    // 8-elem group, total 393216
    const float* src; short* dst; int loc;
    if      (i <  32768) { src = Wq; dst = Wcat;          loc = i; }
    else if (i <  65536) { src = Wk; dst = Wcat + 262144; loc = i - 32768; }
    else if (i <  98304) { src = Wv; dst = Wcat + 524288; loc = i - 65536; }
    else if (i < 131072) { src = Wp; dst = Wpb;           loc = i - 98304; }
    else if (i < 262144) { src = W1; dst = W1b;           loc = i - 131072; }
    else                 { src = W2; dst = W2b;           loc = i - 262144; }
    const float4* p = (const float4*)(src + (size_t)loc * 8);
    float4 a = p[0], b = p[1];
    short8 r;
    r[0]=bf16b(a.x); r[1]=bf16b(a.y); r[2]=bf16b(a.z); r[3]=bf16b(a.w);
    r[4]=bf16b(b.x); r[5]=bf16b(b.y); r[6]=bf16b(b.z); r[7]=bf16b(b.w);
    *(short8*)(dst + (size_t)loc * 8) = r;
}

// ---------------------------------------------------------------- layernorm (f32 in, bf16 out)
__global__ __launch_bounds__(256) void ln_kernel(const float* __restrict__ x,
        const float* __restrict__ g, const float* __restrict__ be,
        short* __restrict__ o)
{
    int row  = blockIdx.x * 4 + (threadIdx.x >> 6);
    int lane = threadIdx.x & 63;
    const float4* xr = (const float4*)(x + (size_t)row * DIM);
    float4 v0 = xr[lane*2], v1 = xr[lane*2+1];
    float s = v0.x+v0.y+v0.z+v0.w + v1.x+v1.y+v1.z+v1.w;
    #pragma unroll
    for (int off = 32; off; off >>= 1) s += __shfl_xor(s, off);
    float mu = s * (1.0f/DIM);
    float d[8] = {v0.x-mu, v0.y-mu, v0.z-mu, v0.w-mu, v1.x-mu, v1.y-mu, v1.z-mu, v1.w-mu};
    float q = 0.f;
    #pragma unroll
    for (int j = 0; j < 8; ++j) q += d[j]*d[j];
    #pragma unroll
    for (int off = 32; off; off >>= 1) q += __shfl_xor(q, off);
    float rs = rsqrtf(q * (1.0f/DIM) + 1e-5f);
    const float4* g4 = (const float4*)g;
    const float4* b4 = (const float4*)be;
    float4 ga = g4[lane*2], gb = g4[lane*2+1];
    float4 ba = b4[lane*2], bb = b4[lane*2+1];
    float gv[8] = {ga.x,ga.y,ga.z,ga.w, gb.x,gb.y,gb.z,gb.w};
    float bv[8] = {ba.x,ba.y,ba.z,ba.w, bb.x,bb.y,bb.z,bb.w};
    short8 r;
    #pragma unroll
    for (int j = 0; j < 8; ++j) r[j] = bf16b(d[j]*rs*gv[j] + bv[j]);
    *(short8*)(o + (size_t)row * DIM + lane*8) = r;
}

// ---------------------------------------------------------------- bf16 MFMA GEMM v4
// = v3 tile/fragment structure + T4 counted-vmcnt pipeline: triple-buffered
// LDS, prefetch 2 K-steps ahead, raw barriers (no vmcnt(0) drain in steady
// state). Per step: B1(read-release) -> STAGE(t+2) -> vmcnt(own batch t
// landed, 2 newer batches in flight) -> B2(all waves landed) -> ds_read+MFMA.
template<int TM, int TAG>
__global__ __launch_bounds__(256) void gemm_v4(
        const short* __restrict__ A, const short* __restrict__ W,
        const float* __restrict__ bias, const float* __restrict__ res,
        float* __restrict__ Cf, short* __restrict__ Cb,
        short* __restrict__ CbK, short* __restrict__ CbV,
        int K, int sa, int sw, int sc, int act, int accum)
{
    constexpr int MI = TM / 32;           // acc fragments per wave in M
    constexpr int ASZ = TM * 32;          // shorts per A buffer
    __shared__ short As[3 * ASZ];
    __shared__ short Ws[3 * 4096];
    int tid = threadIdx.x;
    int m0 = blockIdx.y * TM, n0 = blockIdx.x * 128;
    int w = tid >> 6, lane = tid & 63;
    int wr = (w >> 1) * (TM/2), wc = (w & 1) * 64;
    int lr = lane & 15, lg = lane >> 4;
    int srow = tid >> 2, skoff = (tid & 3) * 8;
    const short* Ab = A + (size_t)(m0 + srow) * sa + skoff;
    const short* Wb = W + (size_t)(n0 + srow) * sw + skoff;

    #define STAGE_G(buf, kk) do { \
        gload16(Ab + (kk),                    As + (buf)*ASZ + tid*8); \
        if constexpr (TM == 128) \
            gload16(Ab + (size_t)64*sa + (kk), As + (buf)*ASZ + 2048 + tid*8); \
        gload16(Wb + (kk),                    Ws + (buf)*4096 + tid*8); \
        gload16(Wb + (size_t)64*sw + (kk),    Ws + (buf)*4096 + 2048 + tid*8); } while(0)

    f32x4 acc[MI][4];
    f32x4 zero = {0.f, 0.f, 0.f, 0.f};
    #pragma unroll
    for (int i = 0; i < MI; ++i)
        #pragma unroll
        for (int j = 0; j < 4; ++j) acc[i][j] = zero;

    int NKB = K >> 5;
    STAGE_G(0, 0);
    STAGE_G(1, 32);
    int cur = 0;
    for (int kb = 0; kb < NKB; ++kb) {
        __builtin_amdgcn_s_barrier();              // reads of buf (cur+2)%3 done everywhere
        asm volatile("" ::: "memory");
        if (kb + 2 < NKB) {
            int nb = cur + 2; if (nb >= 3) nb -= 3;
            STAGE_G(nb, (kb + 2) * 32);
            if constexpr (TM == 128) asm volatile("s_waitcnt vmcnt(8)" ::: "memory");
            else                     asm volatile("s_waitcnt vmcnt(6)" ::: "memory");
        } else if (kb + 1 < NKB) {
            if constexpr (TM == 128) asm volatile("s_waitcnt vmcnt(4)" ::: "memory");
            else                     asm volatile("s_waitcnt vmcnt(3)" ::: "memory");
        } else {
            asm volatile("s_waitcnt vmcnt(0)" ::: "memory");
        }
        __builtin_amdgcn_s_barrier();              // batch kb landed for all waves
        asm volatile("" ::: "memory");
        short8 a[MI], b[4];
        #pragma unroll
        for (int i = 0; i < MI; ++i) a[i] = *(const short8*)(As + cur*ASZ + (wr + i*16 + lr)*32 + lg*8);
        #pragma unroll
        for (int j = 0; j < 4; ++j) b[j] = *(const short8*)(Ws + cur*4096 + (wc + j*16 + lr)*32 + lg*8);
        #pragma unroll
        for (int i = 0; i < MI; ++i)
            #pragma unroll
            for (int j = 0; j < 4; ++j)
                acc[i][j] = __builtin_amdgcn_mfma_f32_16x16x32_bf16(a[i], b[j], acc[i][j], 0, 0, 0);
        cur = (cur + 1 == 3) ? 0 : cur + 1;
    }
    #undef STAGE_G

    #pragma unroll
    for (int i = 0; i < MI; ++i) {
        #pragma unroll
        for (int r = 0; r < 4; ++r) {
            size_t m = (size_t)m0 + wr + i*16 + lg*4 + r;
            #pragma unroll
            for (int j = 0; j < 4; ++j) {
                int n = n0 + wc + j*16 + lr;
                float v = acc[i][j][r];
                if (bias) v += bias[n];
                if (act)  v = gelu_f(v);
                if (CbK) {
                    int seg = n >> 9, nl = n & 511;
                    short* dst = (seg == 0) ? Cb : (seg == 1) ? CbK : CbV;
                    dst[m * 512 + nl] = bf16b(v);
                } else {
                    if (res) v += res[m * sc + n];
                    size_t idx = m * sc + n;
                    if (Cf) { if (accum) Cf[idx] += v; else Cf[idx] = v; }
                    if (Cb) Cb[idx] = bf16b(v);
                }
            }
        }
    }
}

// ---------------------------------------------------------------- bf16 tile transpose V[b][l][d] -> Vt[b][d][l]
__global__ __launch_bounds__(256) void vtrans(const short* __restrict__ V,
                                              short* __restrict__ Vt)
{
    __shared__ short t_s[64][72];
    int l0 = blockIdx.x * 64, d0 = blockIdx.y * 64, b = blockIdx.z;
    int t = threadIdx.x;
    const short* src = V + (size_t)b * SEQ * DIM;
    #pragma unroll
    for (int it = 0; it < 2; ++it) {
        int r = (t >> 3) + it * 32, c = (t & 7) * 8;
        *(short8*)&t_s[r][c] = *(const short8*)(src + (size_t)(l0 + r) * DIM + d0 + c);
    }
    __syncthreads();
    short* dst = Vt + (size_t)b * DIM * SEQ;
    #pragma unroll
    for (int it = 0; it < 2; ++it) {
        int r = (t >> 3) + it * 32, c = (t & 7) * 8;
        short8 v;
        #pragma unroll
        for (int j = 0; j < 8; ++j) v[j] = t_s[c + j][r];
        *(short8*)(dst + (size_t)(d0 + r) * SEQ + l0 + c) = v;
    }
}

// ---------------------------------------------------------------- attention v8 (r10-proven, byte-identical)
__global__ __launch_bounds__(512, 2) void attn_v8(
        const short* __restrict__ Q, const short* __restrict__ K,
        const short* __restrict__ Vt, short* __restrict__ Opart,
        float* __restrict__ Mpart, float* __restrict__ Lpart,
        float scale, const float* __restrict__ scale_ptr,
        const float* __restrict__ gate, int causal, int NC, int ncs)
{
    if (gate && gate[0] == 0.0f) return;
    if (scale_ptr) scale = scale_ptr[0];
    extern __shared__ short lds[];
    short* k_s  = lds;             // [2][32 rows][512 dims] swizzled  64 KB
    short* v_s  = lds + 32768;     // [2][512 d][32 keys] slot16      64 KB
    short* p_s  = lds + 65536;     // [8 waves][16 rows][32]            8 KB
    float* ss_s = (float*)(lds + 69632); // [8 waves][64 lanes][8]     16 KB

    int tid = threadIdx.x, w = tid >> 6, lane = tid & 63;
    int rg = w >> 1, dh = w & 1;
    int lr = lane & 15, lg = lane >> 4;

    int bid = blockIdx.x;
    int c  = bid & (NC - 1);
    int b  = (bid >> ncs) & 1;
    int ip = bid >> (ncs + 1);
    int jj0 = ip, jj1 = 63 - ip;
    int TA = causal ? 2*(ip+1)  : 128;
    int TB = causal ? 2*(64-ip) : 128;
    int Ttot = TA + TB;
    int s0 = (Ttot * c) >> ncs, s1 = (Ttot * (c+1)) >> ncs;

    size_t bofs = (size_t)b * SEQ * DIM;
    size_t vofs = (size_t)b * DIM * SEQ;
    f32x4 zero = {0.f, 0.f, 0.f, 0.f};

    for (int sg = 0; sg < 2; ++sg) {
        int j  = sg ? jj1 : jj0;
        int ta = sg ? (max(s0, TA) - TA) : s0;
        int tb = sg ? (s1 - TA)          : min(s1, TA);
        if (ta >= tb) continue;
        int qw0 = j*64 + rg*16;

        short8 qf[8];                      // own 256-dim half only
        #pragma unroll
        for (int kc = 0; kc < 8; ++kc)
            qf[kc] = *(const short8*)(Q + bofs + (size_t)(qw0 + lr)*DIM
                                      + dh*256 + kc*32 + lg*8);

        f32x4 o[16];
        #pragma unroll
        for (int df = 0; df < 16; ++df) o[df] = zero;
        float mreg[4] = {-1e30f,-1e30f,-1e30f,-1e30f};
        float lreg[4] = {0.f,0.f,0.f,0.f};
        int rowg[4];
        #pragma unroll
        for (int r = 0; r < 4; ++r) rowg[r] = qw0 + lg*4 + r;

        int cur = 0;
        {
            int k0s = ta * KT;
            #pragma unroll
            for (int s4 = 0; s4 < 4; ++s4) {
                int slot = tid + s4*512;
                int row = slot >> 6, cg = slot & 63;
                gload16(K + bofs + (size_t)(k0s + row)*DIM + ((cg ^ (row & 7)) << 3),
                        k_s + slot*8);
                int dpair = slot >> 3, low = slot & 7;
                int d = dpair*2 + (low & 1);
                int kg = (low >> 1) ^ (dpair & 3);
                gload16(Vt + vofs + (size_t)d*SEQ + k0s + kg*8,
                        v_s + slot*8);
            }
        }
        __syncthreads();

        for (int t = ta; t < tb; ++t) {
            int k0 = t * KT;
            if (t + 1 < tb) {              // full-tile prefetch window
                int k0s = (t + 1) * KT;
                int bo = (cur ^ 1) * 16384;
                #pragma unroll
                for (int s4 = 0; s4 < 4; ++s4) {
                    int slot = tid + s4*512;
                    int row = slot >> 6, cg = slot & 63;
                    gload16(K + bofs + (size_t)(k0s + row)*DIM + ((cg ^ (row & 7)) << 3),
                            k_s + bo + slot*8);
                    int dpair = slot >> 3, low = slot & 7;
                    int d = dpair*2 + (low & 1);
                    int kg = (low >> 1) ^ (dpair & 3);
                    gload16(Vt + vofs + (size_t)d*SEQ + k0s + kg*8,
                            v_s + bo + slot*8);
                }
            }
            // ---- QK^T over OWN 256-dim half (16 MFMA)
            f32x4 ss[2];
            ss[0] = zero; ss[1] = zero;
            const short* kb = k_s + cur*16384;
            #pragma unroll
            for (int kc = 0; kc < 8; ++kc) {
                #pragma unroll
                for (int kf = 0; kf < 2; ++kf) {
                    int row = kf*16 + lr;
                    int dg = dh*32 + kc*4 + lg;
                    short8 kk = *(const short8*)(kb + row*512 + ((dg ^ (row & 7)) << 3));
                    ss[kf] = __builtin_amdgcn_mfma_f32_16x16x32_bf16(qf[kc], kk, ss[kf], 0, 0, 0);
                }
            }
            // ---- exchange partials across dh pair (LDS-only sync, no DMA drain)
            *(f32x4*)(ss_s + w*512 + lane*8)     = ss[0];
            *(f32x4*)(ss_s + w*512 + lane*8 + 4) = ss[1];
            asm volatile("s_waitcnt lgkmcnt(0)" ::: "memory");
            __builtin_amdgcn_s_barrier();
            __builtin_amdgcn_sched_barrier(0);
            f32x4 po0 = *(const f32x4*)(ss_s + (w^1)*512 + lane*8);
            f32x4 po1 = *(const f32x4*)(ss_s + (w^1)*512 + lane*8 + 4);
            // ---- sum + scale + causal mask (commutative add -> pair-identical)
            bool needmask = causal && (k0 + KT - 1 > qw0);
            #pragma unroll
            for (int r = 0; r < 4; ++r) {
                float s0v = (ss[0][r] + po0[r]) * scale;
                float s1v = (ss[1][r] + po1[r]) * scale;
                if (needmask) {
                    if (k0 + lr      > rowg[r]) s0v = -1e30f;
                    if (k0 + 16 + lr > rowg[r]) s1v = -1e30f;
                }
                ss[0][r] = s0v; ss[1][r] = s1v;
            }
            // ---- defer-max (T13) online softmax
            float pm[4];
            bool tg = false;
            #pragma unroll
            for (int r = 0; r < 4; ++r) {
                pm[r] = fmaxf(ss[0][r], ss[1][r]);
                tg |= (pm[r] > mreg[r] + 8.0f);
            }
            if (__any(tg)) {
                #pragma unroll
                for (int r = 0; r < 4; ++r) {
                    float v = pm[r];
                    v = fmaxf(v, __shfl_xor(v, 1));
                    v = fmaxf(v, __shfl_xor(v, 2));
                    v = fmaxf(v, __shfl_xor(v, 4));
                    v = fmaxf(v, __shfl_xor(v, 8));
                    float nm = fmaxf(mreg[r], v);
                    float fr = __expf(mreg[r] - nm);
                    mreg[r] = nm;
                    lreg[r] *= fr;
                    #pragma unroll
                    for (int df = 0; df < 16; ++df) o[df][r] *= fr;
                }
            }
            // ---- P = exp(s - m) -> wave-private LDS -> A-frag
            #pragma unroll
            for (int kf = 0; kf < 2; ++kf) {
                #pragma unroll
                for (int r = 0; r < 4; ++r) {
                    float sv = ss[kf][r];
                    float p = (sv < -1e29f) ? 0.0f : __expf(sv - mreg[r]);
                    lreg[r] += p;
                    int row = lg*4 + r;
                    int oct = kf*2 + (lr >> 3);
                    p_s[w*512 + row*32 + ((oct ^ r ^ (lg & 3)) << 3) + (lr & 7)] = bf16b(p);
                }
            }
            short8 pa = *(const short8*)(p_s + w*512 + lr*32
                         + ((lg ^ (lr & 3) ^ ((lr >> 2) & 3)) << 3));
            // ---- PV (own d-half, 16 MFMA)
            const short* vb = v_s + cur*16384;
            #pragma unroll
            for (int df = 0; df < 16; ++df) {
                int d = dh*256 + df*16 + lr;
                int slot16 = (d >> 1)*8 + (((lg ^ ((d >> 1) & 3)) << 1) | (d & 1));
                short8 vv = *(const short8*)(vb + slot16*8);
                o[df] = __builtin_amdgcn_mfma_f32_16x16x32_bf16(pa, vv, o[df], 0, 0, 0);
            }
            __syncthreads();               // full drain: prefetch + LDS
            cur ^= 1;
        }

        // ---- flush partials for (b, j, c)
        #pragma unroll
        for (int r = 0; r < 4; ++r) {
            float v = lreg[r];
            v += __shfl_xor(v, 1);
            v += __shfl_xor(v, 2);
            v += __shfl_xor(v, 4);
            v += __shfl_xor(v, 8);
            lreg[r] = v;
        }
        int slot = (b*64 + j)*NC + c;
        size_t obase = ((size_t)slot*8 + w) * 4096;
        #pragma unroll
        for (int df = 0; df < 16; ++df) {
            short4v pk;
            #pragma unroll
            for (int r = 0; r < 4; ++r) pk[r] = bf16b(o[df][r]);
            *(short4v*)(Opart + obase + df*256 + lane*4) = pk;
        }
        if (dh == 0 && lr == 0) {
            #pragma unroll
            for (int r = 0; r < 4; ++r) {
                Mpart[slot*64 + rg*16 + lg*4 + r] = mreg[r];
                Lpart[slot*64 + rg*16 + lg*4 + r] = lreg[r];
            }
        }
    }
}

// ---------------------------------------------------------------- merge chunk partials
__global__ __launch_bounds__(256) void attn_merge(
        const short* __restrict__ Opart, const float* __restrict__ Mpart,
        const float* __restrict__ Lpart, short* __restrict__ attb,
        float* __restrict__ outf, const float* __restrict__ gate,
        int causal, int NC, int ncs)
{
    if (gate && gate[0] == 0.0f) return;
    __shared__ float wts[8][64];
    int j = blockIdx.x, dh = blockIdx.y, b = blockIdx.z;
    int tid = threadIdx.x;
    int ip = (j < 32) ? j : 63 - j;
    int TA = causal ? 2*(ip+1)  : 128;
    int TB = causal ? 2*(64-ip) : 128;
    int Ttot = TA + TB;
    int jstart = (j < 32) ? 0 : TA;
    int jend   = (j < 32) ? TA : Ttot;
    bool val[8];
    for (int c = 0; c < 8; ++c) {
        int sc = (Ttot * c) >> ncs, ec = (Ttot * (c+1)) >> ncs;
        val[c] = (c < NC) && (sc < jend) && (ec > jstart);
    }
    if (tid < 64) {
        float M = -1e30f;
        for (int c = 0; c < NC; ++c)
            if (val[c]) M = fmaxf(M, Mpart[((b*64 + j)*NC + c)*64 + tid]);
        float L = 0.f;
        for (int c = 0; c < NC; ++c)
            if (val[c]) L += Lpart[((b*64 + j)*NC + c)*64 + tid]
                           * __expf(Mpart[((b*64 + j)*NC + c)*64 + tid] - M);
        float invL = 1.0f / L;
        for (int c = 0; c < NC; ++c)
            wts[c][tid] = val[c]
                ? __expf(Mpart[((b*64 + j)*NC + c)*64 + tid] - M) * invL : 0.0f;
    }
    __syncthreads();
    int wv = tid >> 6, lane = tid & 63, lg = lane >> 4, lr = lane & 15;
    int region = wv*2 + dh;
    for (int df = 0; df < 16; ++df) {
        float acc[4] = {0.f, 0.f, 0.f, 0.f};
        for (int c = 0; c < NC; ++c) {
            if (!val[c]) continue;
            size_t idx = ((size_t)((b*64 + j)*NC + c)*8 + region)*4096 + df*256 + lane*4;
            short4v v = *(const short4v*)(Opart + idx);
            #pragma unroll
            for (int r = 0; r < 4; ++r)
                acc[r] += wts[c][wv*16 + lg*4 + r] * bf16f(v[r]);
        }
        #pragma unroll
        for (int r = 0; r < 4; ++r) {
            int row = j*64 + wv*16 + lg*4 + r;
            int d = dh*256 + df*16 + lr;
            size_t oidx = (size_t)b*SEQ*DIM + (size_t)row*DIM + d;
            if (attb) attb[oidx] = bf16b(acc[r]);
            else      outf[oidx] += acc[r];
        }
    }
}

// ---------------------------------------------------------------- last-row scores (bf16 in)
__global__ __launch_bounds__(256) void lastrow_scores(const short* __restrict__ Q,
        const short* __restrict__ K, float* __restrict__ slast)
{
    __shared__ float q_l[DIM];
    int b = blockIdx.y;
    int m = blockIdx.x * 256 + threadIdx.x;
    for (int i = threadIdx.x; i < DIM; i += 256)
        q_l[i] = bf16f(Q[((size_t)b*SEQ + SEQ-1)*DIM + i]);
    __syncthreads();
    const short* kr = K + ((size_t)b*SEQ + m) * DIM;
    float s = 0.f;
    for (int d = 0; d < DIM; d += 8) {
        short8 k8 = *(const short8*)(kr + d);
        #pragma unroll
        for (int j = 0; j < 8; ++j) s += q_l[d + j] * bf16f(k8[j]);
    }
    slast[(size_t)b*SEQ + m] = s * RSQRT_D;
}

// ---------------------------------------------------------------- entropy of last-row softmax
__global__ __launch_bounds__(256) void entropy_kernel(const float* __restrict__ slast,
        float* __restrict__ H)
{
    __shared__ float sm[4];
    int b = blockIdx.x, t = threadIdx.x;
    const float* s = slast + (size_t)b * SEQ;
    float v[16];
    float mx = -1e30f;
    #pragma unroll
    for (int j = 0; j < 16; ++j) { v[j] = s[t + j*256]; mx = fmaxf(mx, v[j]); }
    #pragma unroll
    for (int o = 32; o; o >>= 1) mx = fmaxf(mx, __shfl_xor(mx, o));
    __syncthreads();
    if ((t & 63) == 0) sm[t >> 6] = mx;
    __syncthreads();
    mx = fmaxf(fmaxf(sm[0], sm[1]), fmaxf(sm[2], sm[3]));
    float se = 0.f;
    #pragma unroll
    for (int j = 0; j < 16; ++j) { v[j] = expf(v[j] - mx); se += v[j]; }
    se = blk_sum256(se, sm);
    float inv = 1.0f / se;
    float h = 0.f;
    #pragma unroll
    for (int j = 0; j < 16; ++j) {
        float p = fmaxf(v[j] * inv, 1e-9f);
        h -= p * logf(p);
    }
    h = blk_sum256(h, sm);
    if (t == 0) H[b] = h;
}

// ---------------------------------------------------------------- K mean partials (bf16 in)
__global__ __launch_bounds__(256) void krep_partial(const short* __restrict__ K,
        float* __restrict__ part)
{
    int b = blockIdx.y, j = blockIdx.x, t = threadIdx.x;
    size_t base = ((size_t)b*SEQ + (size_t)j*64) * DIM;
    float s0 = 0.f, s1 = 0.f;
    for (int r = 0; r < 64; ++r) {
        s0 += bf16f(K[base + (size_t)r*DIM + t]);
        s1 += bf16f(K[base + (size_t)r*DIM + t + 256]);
    }
    size_t o = (size_t)(b*64 + j) * DIM;
    part[o + t] = s0; part[o + t + 256] = s1;
}

// ---------------------------------------------------------------- gate scalar kernel
__global__ __launch_bounds__(256) void scalar_kernel(const short* __restrict__ Qb,
        const float* __restrict__ part, const float* __restrict__ Hent,
        float* __restrict__ gsc)
{
    __shared__ float sm[4];
    __shared__ float sims[BATCH];
    int t = threadIdx.x;
    float qv0 = 0.5f*(bf16f(Qb[((size_t)0*SEQ + SEQ-1)*DIM + t])     + bf16f(Qb[((size_t)1*SEQ + SEQ-1)*DIM + t]));
    float qv1 = 0.5f*(bf16f(Qb[((size_t)0*SEQ + SEQ-1)*DIM + t+256]) + bf16f(Qb[((size_t)1*SEQ + SEQ-1)*DIM + t+256]));
    for (int b = 0; b < BATCH; ++b) {
        float k0 = 0.f, k1 = 0.f;
        for (int j = 0; j < 64; ++j) {
            k0 += part[(size_t)(b*64+j)*DIM + t];
            k1 += part[(size_t)(b*64+j)*DIM + t + 256];
        }
        k0 *= (1.0f/SEQ); k1 *= (1.0f/SEQ);
        float num = blk_sum256(qv0*k0 + qv1*k1, sm);
        float qq  = blk_sum256(qv0*qv0 + qv1*qv1, sm);
        float kk  = blk_sum256(k0*k0 + k1*k1, sm);
        if (t == 0) {
            float na = fmaxf(sqrtf(qq), 1e-8f);
            float nb = fmaxf(sqrtf(kk), 1e-8f);
            sims[b] = num / (na * nb);
        }
        __syncthreads();
    }
    if (t == 0) {
        float H0 = Hent[0], H1 = Hent[1];
        float mn = fminf(H0, H1), mx = fmaxf(H0, H1);
        float den = (mx - mn) + 1e-9f;
        float Hm = 0.5f*((H0 - mn)/den + (H1 - mn)/den);
        float T  = 0.6f + (1.6f - 0.6f) * Hm;
        float th = 0.9f - (0.9f - 0.5f) * Hm;
        float s  = 0.5f * (sims[0] + sims[1]);
        gsc[0] = (s >= th) ? 1.0f : 0.0f;
        gsc[1] = 1.0f / (sqrtf((float)DIM) * T);
    }
}

// ---------------------------------------------------------------- launch
extern "C" void kernel_launch(void* const* d_in, const int* in_sizes, int n_in,
                              void* d_out, int out_size, void* d_ws, size_t ws_size,
                              hipStream_t stream)
{
    (void)in_sizes; (void)n_in; (void)out_size;
    const float* x     = (const float*)d_in[0];
    const float* Wq    = (const float*)d_in[1];
    const float* Wk    = (const float*)d_in[2];
    const float* Wv    = (const float*)d_in[3];
    const float* Wp    = (const float*)d_in[4];
    const float* W1    = (const float*)d_in[5];
    const float* b1    = (const float*)d_in[6];
    const float* W2    = (const float*)d_in[7];
    const float* b2    = (const float*)d_in[8];
    const float* gamma = (const float*)d_in[9];
    const float* beta  = (const float*)d_in[10];
    float* out = (float*)d_out;

    const size_t NT = (size_t)NROWS * DIM;   // 4,194,304
    short* bws   = (short*)d_ws;
    short* Qbf   = bws;                      // 4M
    short* Kbf   = Qbf + NT;                 // 4M
    short* Vt    = Kbf + NT;                 // 4M
    short* att   = Vt + NT;                  // 4M (also V pre-transpose temp)
    short* Wcat  = att + NT;                 // 786432
    short* Wpb   = Wcat + 786432;
    short* W1b   = Wpb + 262144;
    short* W2b   = W1b + 1048576;
    float* slast = (float*)(W2b + 1048576);  // 8192
    float* Hent  = slast + 8192;             // 8
    float* kpart = Hent + 8;                 // 65536
    float* gsc   = kpart + 65536;            // 8

    const int NC = 4, ncs = 2;
    size_t mlsz = (size_t)128 * NC * 64;
    float* Mpart = gsc + 8;
    float* Lpart = Mpart + mlsz;
    short* xn_bf = (short*)(Lpart + mlsz);   // 4M (dead during attention)
    short* h1    = xn_bf + NT;               // FFN hidden (8M half / 16.8M full)
    short* Opart = xn_bf;                    // overlaps xn+h1+beyond

    // full-FFN path needs h1 = NROWS*FF shorts after xn_bf
    size_t ffn_full_end = ((size_t)(h1 - bws) + (size_t)NROWS * FF) * 2;
    int ffn_full = (ws_size >= ffn_full_end + 1024);

    const int ATTN_LDS = 155648;             // 64K k + 64K v + 8K p + 16K ss
    hipFuncSetAttribute((const void*)attn_v8,
                        hipFuncAttributeMaxDynamicSharedMemorySize, ATTN_LDS);

    f2bf_all<<<1536, 256, 0, stream>>>(Wq, Wk, Wv, Wp, W1, W2, Wcat, Wpb, W1b, W2b);

    ln_kernel<<<NROWS/4, 256, 0, stream>>>(x, gamma, beta, xn_bf);

    // fused QKV projection: [8192,512] x [1536,512]^T, routed outputs
    gemm_v4<128,0><<<dim3(1536/128, NROWS/128), 256, 0, stream>>>(
        xn_bf, Wcat, nullptr, nullptr, nullptr, Qbf, Kbf, att,
        DIM, DIM, DIM, DIM, 0, 0);
    vtrans<<<dim3(SEQ/64, DIM/64, BATCH), 256, 0, stream>>>(att, Vt);
    // xn_bf/h1 dead -> Opart may overwrite them

    attn_v8<<<64*NC, 512, ATTN_LDS, stream>>>(Qbf, Kbf, Vt, Opart, Mpart, Lpart,
                                              RSQRT_D, nullptr, nullptr, 1, NC, ncs);
    attn_merge<<<dim3(64, 2, BATCH), 256, 0, stream>>>(Opart, Mpart, Lpart, att, nullptr,
                                                       nullptr, 1, NC, ncs);

    lastrow_scores<<<dim3(SEQ/256, BATCH), 256, 0, stream>>>(Qbf, Kbf, slast);
    entropy_kernel<<<BATCH, 256, 0, stream>>>(slast, Hent);

    // ctx = x + att @ Wp^T (fp32 into d_out) -- TM=64: 512 blocks
    gemm_v4<64,1><<<dim3(DIM/128, NROWS/64), 256, 0, stream>>>(
        att, Wpb, nullptr, x, out, nullptr, nullptr, nullptr,
        DIM, DIM, DIM, DIM, 0, 0);

    // h = LN(ctx) -> xn_bf (Opart dead after merge)
    ln_kernel<<<NROWS/4, 256, 0, stream>>>(out, gamma, beta, xn_bf);

    if (ffn_full) {
        gemm_v4<128,2><<<dim3(FF/128, NROWS/128), 256, 0, stream>>>(
            xn_bf, W1b, b1, nullptr, nullptr, h1, nullptr, nullptr,
            DIM, DIM, DIM, FF, 1, 0);
        gemm_v4<64,3><<<dim3(DIM/128, NROWS/64), 256, 0, stream>>>(
            h1, W2b, b2, nullptr, out, nullptr, nullptr, nullptr,
            FF, FF, FF, DIM, 0, 1);
    } else {
        for (int c = 0; c < 2; ++c) {
            gemm_v4<128,2><<<dim3(1024/128, NROWS/128), 256, 0, stream>>>(
                xn_bf, W1b + (size_t)c*1024*DIM, b1 + c*1024, nullptr,
                nullptr, h1, nullptr, nullptr,
                DIM, DIM, DIM, 1024, 1, 0);
            gemm_v4<64,3><<<dim3(DIM/128, NROWS/64), 256, 0, stream>>>(
                h1, W2b + (size_t)c*1024, (c == 0) ? b2 : nullptr, nullptr,
                out, nullptr, nullptr, nullptr,
                1024, 1024, FF, DIM, 0, 1);
        }
    }

    krep_partial<<<dim3(64, BATCH), 256, 0, stream>>>(Kbf, kpart);
    scalar_kernel<<<1, 256, 0, stream>>>(Qbf, kpart, Hent, gsc);

    // gated re-attention (non-causal, temperature), accumulate fp32 into out
    attn_v8<<<64*NC, 512, ATTN_LDS, stream>>>(Qbf, Kbf, Vt, Opart, Mpart, Lpart,
                                              0.0f, gsc + 1, gsc, 0, NC, ncs);
    attn_merge<<<dim3(64, 2, BATCH), 256, 0, stream>>>(Opart, Mpart, Lpart, nullptr, out,
                                                       gsc, 0, NC, ncs);
}